// Round 12
// baseline (171.975 us; speedup 1.0000x reference)
//
#include <hip/hip_runtime.h>
#include <hip/hip_bf16.h>
#include <cstdint>
#include <cstddef>

using bf16x8   = __attribute__((ext_vector_type(8))) short;
using f32x4    = __attribute__((ext_vector_type(4))) float;
using f32x16   = __attribute__((ext_vector_type(16))) float;
using ushort8  = __attribute__((ext_vector_type(8))) unsigned short;
using ushort4v = __attribute__((ext_vector_type(4))) unsigned short;
using float4v  = __attribute__((ext_vector_type(4))) float;
using float2v  = __attribute__((ext_vector_type(2))) float;

#define MFMA16(a,b,c) __builtin_amdgcn_mfma_f32_16x16x32_bf16((a),(b),(c),0,0,0)
#define MFMA32(a,b,c) __builtin_amdgcn_mfma_f32_32x32x16_bf16((a),(b),(c),0,0,0)

#define QSCALE 0.18033688011112042f   // log2(e)/8

__device__ __forceinline__ unsigned short f2bf(float f){
    union { float f; unsigned u; } v; v.f = f;
    unsigned r = v.u + 0x7FFFu + ((v.u >> 16) & 1u);
    return (unsigned short)(r >> 16);
}

__device__ __forceinline__ int cvtpk(float lo, float hi){
    int r;
    asm volatile("v_cvt_pk_bf16_f32 %0, %1, %2" : "=v"(r) : "v"(lo), "v"(hi));
    return r;
}

#if __has_builtin(__builtin_amdgcn_permlane32_swap)
__device__ __forceinline__ void plswap(int &a, int &b){
    auto r = __builtin_amdgcn_permlane32_swap(a, b, false, false);
    a = r[0]; b = r[1];
}
#else
__device__ __forceinline__ void plswap(int &a, int &b){
    int ta = __shfl_xor(a, 32), tb = __shfl_xor(b, 32);
    bool hi = ((threadIdx.x & 63) >= 32);
    int na = hi ? tb : a;
    int nb = hi ? b  : ta;
    a = na; b = nb;
}
#endif

__device__ __forceinline__ void gload16(const unsigned short* g, unsigned short* l){
    __builtin_amdgcn_global_load_lds(
        (const __attribute__((address_space(1))) void*)g,
        (__attribute__((address_space(3))) void*)l,
        16, 0, 0);
}

// ---------------------------------------------------------------- GN partial stats + wconv merged
__global__ __launch_bounds__(256) void gn_stats_wconv(const float* __restrict__ x,
                                                      float2v* __restrict__ parts,
                                                      const float* __restrict__ w0, const float* __restrict__ w1,
                                                      const float* __restrict__ w2, const float* __restrict__ w3,
                                                      unsigned short* wqk, unsigned short* wv, unsigned short* wo){
    int bid = blockIdx.x;
    if (bid < 512){
        const float4v* p4 = (const float4v*)(x + (size_t)bid * 8192);
        float s = 0.f, ss = 0.f;
        #pragma unroll
        for (int i = 0; i < 8; i++){
            float4v v = p4[i*256 + threadIdx.x];
            s  += v[0]+v[1]+v[2]+v[3];
            ss += v[0]*v[0]+v[1]*v[1]+v[2]*v[2]+v[3]*v[3];
        }
        __shared__ float ls[4], lss[4];
        int lane = threadIdx.x & 63, w = threadIdx.x >> 6;
        #pragma unroll
        for (int o = 32; o > 0; o >>= 1){ s += __shfl_down(s, o); ss += __shfl_down(ss, o); }
        if (lane == 0){ ls[w] = s; lss[w] = ss; }
        __syncthreads();
        if (threadIdx.x == 0){
            float2v p;
            p[0] = ls[0]+ls[1]+ls[2]+ls[3];
            p[1] = lss[0]+lss[1]+lss[2]+lss[3];
            parts[bid] = p;
        }
    } else {
        int i2 = bid - 512;
        int y = i2 >> 8, bx = i2 & 255;
        const float* src; unsigned short* dst; float sc = 1.0f;
        switch (y){
            case 0: src = w0; dst = wqk;          sc = QSCALE; break;
            case 1: src = w1; dst = wqk + 512*512; break;
            case 2: src = w2; dst = wv; break;
            default: src = w3; dst = wo; break;
        }
        int i = (bx*256 + threadIdx.x) * 4;
        float4v v = *(const float4v*)(src + i);
        ushort4v o;
        #pragma unroll
        for (int j = 0; j < 4; j++) o[j] = f2bf(v[j]*sc);
        *(ushort4v*)(dst + i) = o;
    }
}

// normalize + transpose; folds the 8 partials per group inline (deterministic).
__global__ __launch_bounds__(256) void gn_apply(const float* __restrict__ x,
                                                const float2v* __restrict__ parts,
                                                const float* __restrict__ gw,
                                                const float* __restrict__ gb,
                                                unsigned short* __restrict__ xn){
    int b = blockIdx.z, c0 = blockIdx.y * 64, n0 = blockIdx.x * 64;
    __shared__ unsigned short tile[64][68];
    __shared__ float gmean[4], grstd[4];
    if (threadIdx.x < 4){
        int g = b*32 + (c0 >> 4) + threadIdx.x;
        float s = 0.f, ss = 0.f;
        #pragma unroll
        for (int e = 0; e < 8; e++){
            float2v p = parts[g*8 + e];
            s += p[0]; ss += p[1];
        }
        float m = s * (1.f/65536.f);
        float var = ss * (1.f/65536.f) - m*m;
        gmean[threadIdx.x] = m;
        grstd[threadIdx.x] = rsqrtf(var + 1e-5f);
    }
    __syncthreads();
    for (int i = threadIdx.x; i < 64*16; i += 256){
        int row = i >> 4, f4 = i & 15;
        int c = c0 + row;
        int gl = row >> 4;
        float rs = grstd[gl];
        float wgt = gw[c] * rs;
        float bia = gb[c] - gmean[gl] * wgt;
        float4v v = *(const float4v*)(x + ((size_t)(b*512 + c))*4096 + n0 + f4*4);
        ushort4v o;
        #pragma unroll
        for (int j = 0; j < 4; j++) o[j] = f2bf(v[j]*wgt + bia);
        *(ushort4v*)&tile[row][f4*4] = o;
    }
    __syncthreads();
    for (int i = threadIdx.x; i < 64*8; i += 256){
        int nr = i >> 3, c8 = i & 7;
        ushort8 o;
        #pragma unroll
        for (int j = 0; j < 8; j++) o[j] = tile[c8*8 + j][nr];
        *(ushort8*)(xn + ((size_t)(b*4096 + n0 + nr))*512 + c0 + c8*8) = o;
    }
}

// ---------------------------------------------------------------- fused QKV projections
__global__ __launch_bounds__(256) void gemm_qkv(const unsigned short* __restrict__ xn,
                                                const unsigned short* __restrict__ wqk,
                                                const unsigned short* __restrict__ Wv,
                                                const float* __restrict__ bq,
                                                const float* __restrict__ bk,
                                                const float* __restrict__ bv,
                                                unsigned short* __restrict__ Q,
                                                unsigned short* __restrict__ K,
                                                unsigned short* __restrict__ Vt){
    __shared__ unsigned short Al[128*32];
    __shared__ unsigned short Bl[128*32];
    int bid = blockIdx.x;
    int t = threadIdx.x, lane = t & 63, w = t >> 6;
    int wr = w >> 1, wc = w & 1;
    int lr = lane >> 2, lc = lane & 3;

    if (bid < 512){
        int m0 = (bid & 63) * 128, n0 = (bid >> 6) * 128;
        f32x4 acc[4][4] = {};
        const unsigned short* Asrc = xn  + (size_t)(m0 + w*32 + lr)*512 + lc*8;
        const unsigned short* Bsrc = wqk + (size_t)(n0 + w*32 + lr)*512 + lc*8;
        unsigned short* Adst = &Al[(w*32)*32];
        unsigned short* Bdst = &Bl[(w*32)*32];

        for (int ks = 0; ks < 16; ks++){
            gload16(Asrc + ks*32,          Adst);
            gload16(Asrc + ks*32 + 16*512, Adst + 16*32);
            gload16(Bsrc + ks*32,          Bdst);
            gload16(Bsrc + ks*32 + 16*512, Bdst + 16*32);
            asm volatile("s_waitcnt vmcnt(0)" ::: "memory");
            __syncthreads();
            bf16x8 a[4], b[4];
            #pragma unroll
            for (int mi = 0; mi < 4; mi++) a[mi] = *(bf16x8*)&Al[(wr*64 + mi*16 + (lane&15))*32 + (lane>>4)*8];
            #pragma unroll
            for (int ni = 0; ni < 4; ni++) b[ni] = *(bf16x8*)&Bl[(wc*64 + ni*16 + (lane&15))*32 + (lane>>4)*8];
            #pragma unroll
            for (int mi = 0; mi < 4; mi++)
                #pragma unroll
                for (int ni = 0; ni < 4; ni++)
                    acc[mi][ni] = MFMA16(a[mi], b[ni], acc[mi][ni]);
            __syncthreads();
        }

        int cK = n0 >> 9;
        const float* bias = cK ? bk : bq;
        unsigned short* dst0 = cK ? K : Q;
        float bsc = cK ? 1.0f : QSCALE;
        #pragma unroll
        for (int mi = 0; mi < 4; mi++)
            #pragma unroll
            for (int ni = 0; ni < 4; ni++)
                #pragma unroll
                for (int r = 0; r < 4; r++){
                    int mrow = m0 + wr*64 + mi*16 + (lane>>4)*4 + r;
                    int col  = (n0 & 511) + wc*64 + ni*16 + (lane&15);
                    int b_ = mrow >> 12, n = mrow & 4095;
                    int h = col >> 6, d = col & 63;
                    float v = acc[mi][ni][r] + bias[col]*bsc;
                    dst0[(size_t)((b_*8+h)*4096 + n)*64 + d] = f2bf(v);
                }
    } else {
        int i2 = bid - 512;
        int m0 = (i2 >> 6) * 64, n0 = (i2 & 63) * 128;
        f32x4 acc[2][4] = {};
        const unsigned short* Asrc = Wv + (size_t)(m0 + w*16 + lr)*512 + lc*8;
        const unsigned short* Bsrc = xn + (size_t)(n0 + w*32 + lr)*512 + lc*8;
        unsigned short* Adst = &Al[(w*16)*32];
        unsigned short* Bdst = &Bl[(w*32)*32];

        for (int ks = 0; ks < 16; ks++){
            gload16(Asrc + ks*32,          Adst);
            gload16(Bsrc + ks*32,          Bdst);
            gload16(Bsrc + ks*32 + 16*512, Bdst + 16*32);
            asm volatile("s_waitcnt vmcnt(0)" ::: "memory");
            __syncthreads();
            bf16x8 a[2], b[4];
            #pragma unroll
            for (int mi = 0; mi < 2; mi++) a[mi] = *(bf16x8*)&Al[(wr*32 + mi*16 + (lane&15))*32 + (lane>>4)*8];
            #pragma unroll
            for (int ni = 0; ni < 4; ni++) b[ni] = *(bf16x8*)&Bl[(wc*64 + ni*16 + (lane&15))*32 + (lane>>4)*8];
            #pragma unroll
            for (int mi = 0; mi < 2; mi++)
                #pragma unroll
                for (int ni = 0; ni < 4; ni++)
                    acc[mi][ni] = MFMA16(a[mi], b[ni], acc[mi][ni]);
            __syncthreads();
        }
        #pragma unroll
        for (int mi = 0; mi < 2; mi++)
            #pragma unroll
            for (int ni = 0; ni < 4; ni++)
                #pragma unroll
                for (int r = 0; r < 4; r++){
                    int row  = m0 + wr*32 + mi*16 + (lane>>4)*4 + r;
                    int colm = n0 + wc*64 + ni*16 + (lane&15);
                    int b_ = colm >> 12, n = colm & 4095;
                    int h = row >> 6, d = row & 63;
                    float v = acc[mi][ni][r] + bv[row];
                    Vt[(size_t)((b_*8+h)*64 + d)*4096 + n] = f2bf(v);
                }
    }
}

// ---------------------------------------------------------------- output projection + residual
__global__ __launch_bounds__(256) void gemm_o2(const unsigned short* __restrict__ Wo,
                                               const unsigned short* __restrict__ Om,
                                               const float* __restrict__ bo,
                                               const float* __restrict__ resid,
                                               float* __restrict__ outp){
    __shared__ unsigned short Al[64*32];
    __shared__ unsigned short Bl[128*32];
    int t = threadIdx.x, lane = t & 63, w = t >> 6;
    int wr = w >> 1, wc = w & 1;
    int m0 = blockIdx.y * 64, n0 = blockIdx.x * 128;
    int lr = lane >> 2, lc = lane & 3;
    f32x4 acc[2][4] = {};

    const unsigned short* Asrc = Wo + (size_t)(m0 + w*16 + lr)*512 + lc*8;
    const unsigned short* Bsrc = Om + (size_t)(n0 + w*32 + lr)*512 + lc*8;
    unsigned short* Adst = &Al[(w*16)*32];
    unsigned short* Bdst = &Bl[(w*32)*32];

    for (int ks = 0; ks < 16; ks++){
        gload16(Asrc + ks*32,          Adst);
        gload16(Bsrc + ks*32,          Bdst);
        gload16(Bsrc + ks*32 + 16*512, Bdst + 16*32);
        asm volatile("s_waitcnt vmcnt(0)" ::: "memory");
        __syncthreads();
        bf16x8 a[2], b[4];
        #pragma unroll
        for (int mi = 0; mi < 2; mi++) a[mi] = *(bf16x8*)&Al[(wr*32 + mi*16 + (lane&15))*32 + (lane>>4)*8];
        #pragma unroll
        for (int ni = 0; ni < 4; ni++) b[ni] = *(bf16x8*)&Bl[(wc*64 + ni*16 + (lane&15))*32 + (lane>>4)*8];
        #pragma unroll
        for (int mi = 0; mi < 2; mi++)
            #pragma unroll
            for (int ni = 0; ni < 4; ni++)
                acc[mi][ni] = MFMA16(a[mi], b[ni], acc[mi][ni]);
        __syncthreads();
    }
    #pragma unroll
    for (int mi = 0; mi < 2; mi++)
        #pragma unroll
        for (int ni = 0; ni < 4; ni++)
            #pragma unroll
            for (int r = 0; r < 4; r++){
                int row  = m0 + wr*32 + mi*16 + (lane>>4)*4 + r;
                int colm = n0 + wc*64 + ni*16 + (lane&15);
                int b_ = colm >> 12, n = colm & 4095;
                size_t oi = ((size_t)(b_*512 + row))*4096 + n;
                outp[oi] = acc[mi][ni][r] + bo[row] + resid[oi];
            }
}

// ---------------------------------------------------------------- flash attention v10: barrier-free + 3 waves/SIMD
// Same wave-local structure as attn9 but V single-buffered (stage V(t+1) issued
// after PV(t) reads; DMA return lands >>100cyc later - validated in attn8).
// LDS 24KB -> 6 blocks/CU -> 3 waves/SIMD. FIFO queue: prologue [K0,V0,K1];
// per-tile end issues [V(t+1), K(t+2)]; tile-top vmcnt(4).
__global__ __launch_bounds__(128, 3) void attn10(const unsigned short* __restrict__ Q,
                                                 const unsigned short* __restrict__ K,
                                                 const unsigned short* __restrict__ Vt,
                                                 unsigned short* __restrict__ O){
    int bid = blockIdx.x;
    int idx = bid >> 3;
    int bh = ((bid & 7) << 1) | (idx >> 6);
    int qt = idx & 63;
    int t = threadIdx.x, lane = t & 63, w = t >> 6;   // w = kv-half
    int ln = lane & 31, hi = lane >> 5;
    int q0 = qt * 64;

    __shared__ unsigned short Kl[2][64*64];        // 16 KB: [buf][kv 64][d 64], wave w owns rows w*32..
    __shared__ unsigned short Vl[2][64*32];        // 8 KB:  [wave][d 64][kv 32] single-buffered

    const unsigned short* Qb = Q  + (size_t)bh * 4096 * 64;
    const unsigned short* Kb = K  + (size_t)bh * 4096 * 64;
    const unsigned short* Vb = Vt + (size_t)bh * 64 * 4096;

    bf16x8 bqa[4], bqb[4];
    #pragma unroll
    for (int dsub = 0; dsub < 4; dsub++){
        bqa[dsub] = *(const bf16x8*)(Qb + (size_t)(q0 + ln)*64      + dsub*16 + hi*8);
        bqb[dsub] = *(const bf16x8*)(Qb + (size_t)(q0 + 32 + ln)*64 + dsub*16 + hi*8);
    }

    // K staging map (8 rows x 128B per gload16, slot XOR row)
    int srow = lane >> 3;
    int sswz = (lane & 7) ^ srow;
    // V staging map (16 rows x 64B per gload16): d = i*16 + (lane>>2), phys slot = lane&3,
    // logical kv-slot s = p ^ ((d>>1)&3)
    int vdl = lane >> 2;
    int vsl = (lane & 3) ^ ((vdl >> 1) & 3);

    auto stageK = [&](int kt){
        int kv0 = kt * 64;
        unsigned short* kdst = &Kl[kt & 1][0];
        #pragma unroll
        for (int i = 0; i < 4; i++){
            int r0 = w*32 + i*8;
            gload16(Kb + (size_t)(kv0 + r0 + srow)*64 + sswz*8, kdst + r0*64);
        }
    };
    auto stageV = [&](int kt){
        int kv0 = kt * 64;
        unsigned short* vdst = &Vl[w][0];
        #pragma unroll
        for (int i = 0; i < 4; i++)
            gload16(Vb + (size_t)(i*16 + vdl)*4096 + kv0 + w*32 + vsl*8, vdst + i*512);
    };

    // prologue FIFO: [K0, V0, K1]
    stageK(0);
    stageV(0);
    stageK(1);

    f32x16 o0a, o1a, o0b, o1b, z;
    #pragma unroll
    for (int r = 0; r < 16; r++){ o0a[r]=0.f; o1a[r]=0.f; o0b[r]=0.f; o1b[r]=0.f; z[r]=0.f; }
    float lsA = 0.f, lsB = 0.f;

    const char* KbA = (const char*)&Kl[0][0] + (w*32 + ln)*128;
    int swzr = (ln & 7) << 4;
    const char* VbW = (const char*)&Vl[w][0];
    int vrswz = (ln >> 1) & 3;

    for (int kt = 0; kt < 64; kt++){
        if (kt < 63) asm volatile("s_waitcnt vmcnt(4)" ::: "memory");
        else         asm volatile("s_waitcnt vmcnt(0)" ::: "memory");
        __builtin_amdgcn_sched_barrier(0);

        int kboff = (kt & 1) * (64*64*2);

        // ---- QK^T (swapped), wave-local K rows
        f32x16 sA, sB;
        {
            int cb = (hi*16) ^ swzr;
            bf16x8 ak = *(const bf16x8*)(KbA + kboff + cb);
            sA = MFMA32(ak, bqa[0], z);
            sB = MFMA32(ak, bqb[0], z);
        }
        __builtin_amdgcn_s_setprio(1);
        #pragma unroll
        for (int dsub = 1; dsub < 4; dsub++){
            int cb = (dsub*32 + hi*16) ^ swzr;
            bf16x8 ak = *(const bf16x8*)(KbA + kboff + cb);
            sA = MFMA32(ak, bqa[dsub], sA);
            sB = MFMA32(ak, bqb[dsub], sB);
        }
        __builtin_amdgcn_s_setprio(0);

        // ---- p = exp2(s); row-sums
        #pragma unroll
        for (int r = 0; r < 16; r++){ sA[r] = __builtin_amdgcn_exp2f(sA[r]); lsA += sA[r]; }
        #pragma unroll
        for (int r = 0; r < 16; r++){ sB[r] = __builtin_amdgcn_exp2f(sB[r]); lsB += sB[r]; }

        // ---- PV (swapped), wave-local V bank
        __builtin_amdgcn_s_setprio(1);
        #pragma unroll
        for (int hsel = 0; hsel < 2; hsel++){
            int obp = hsel * 8;
            int a0 = cvtpk(sA[obp+0], sA[obp+1]);
            int a1 = cvtpk(sA[obp+2], sA[obp+3]);
            int c0 = cvtpk(sA[obp+4], sA[obp+5]);
            int c1 = cvtpk(sA[obp+6], sA[obp+7]);
            plswap(a0, c0);
            plswap(a1, c1);
            union { int i[4]; bf16x8 v; } fuA;
            fuA.i[0] = a0; fuA.i[1] = a1; fuA.i[2] = c0; fuA.i[3] = c1;

            int d0 = cvtpk(sB[obp+0], sB[obp+1]);
            int d1 = cvtpk(sB[obp+2], sB[obp+3]);
            int e0 = cvtpk(sB[obp+4], sB[obp+5]);
            int e1 = cvtpk(sB[obp+6], sB[obp+7]);
            plswap(d0, e0);
            plswap(d1, e1);
            union { int i[4]; bf16x8 v; } fuB;
            fuB.i[0] = d0; fuB.i[1] = d1; fuB.i[2] = e0; fuB.i[3] = e1;

            int p0 = (((hsel*2 + hi) ^ vrswz) << 4);
            bf16x8 av0 = *(const bf16x8*)(VbW + ln*64 + p0);
            bf16x8 av1 = *(const bf16x8*)(VbW + (32 + ln)*64 + p0);
            o0a = MFMA32(av0, fuA.v, o0a);
            o1a = MFMA32(av1, fuA.v, o1a);
            o0b = MFMA32(av0, fuB.v, o0b);
            o1b = MFMA32(av1, fuB.v, o1b);
        }
        __builtin_amdgcn_s_setprio(0);

        // issue next: V(t+1) (after PV reads - program order), then K(t+2)
        __builtin_amdgcn_sched_barrier(0);
        if (kt < 63) stageV(kt + 1);
        if (kt < 62) stageK(kt + 2);
        __builtin_amdgcn_sched_barrier(0);
    }

    // ---- merge kv-halves via LDS, normalize, store
    lsA += __shfl_xor(lsA, 32);
    lsB += __shfl_xor(lsB, 32);
    __syncthreads();
    float* m1 = (float*)&Kl[0][0];   // 4096 floats: o0a|o1a|o0b|o1b
    float* m2 = (float*)&Vl[0][0];   // 2048 floats: row-sums
    if (w == 1){
        #pragma unroll
        for (int r = 0; r < 16; r++){
            m1[r*64 + lane]        = o0a[r];
            m1[1024 + r*64 + lane] = o1a[r];
            m1[2048 + r*64 + lane] = o0b[r];
            m1[3072 + r*64 + lane] = o1b[r];
        }
        if (hi == 0){ m2[ln] = lsA; m2[32 + ln] = lsB; }
    }
    __syncthreads();
    if (w == 0){
        #pragma unroll
        for (int r = 0; r < 16; r++){
            o0a[r] += m1[r*64 + lane];
            o1a[r] += m1[1024 + r*64 + lane];
            o0b[r] += m1[2048 + r*64 + lane];
            o1b[r] += m1[3072 + r*64 + lane];
        }
        float rA = 1.0f / (lsA + m2[ln]);
        float rB = 1.0f / (lsB + m2[32 + ln]);
        int b = bh >> 3, h = bh & 7;
        unsigned short* dstA = O + (size_t)(b*4096 + q0 + ln)*512      + h*64;
        unsigned short* dstB = O + (size_t)(b*4096 + q0 + 32 + ln)*512 + h*64;
        #pragma unroll
        for (int m = 0; m < 2; m++){
            const f32x16& ovA = m ? o1a : o0a;
            const f32x16& ovB = m ? o1b : o0b;
            #pragma unroll
            for (int g = 0; g < 4; g++){
                int d = m*32 + g*8 + hi*4;
                ushort4v pkA, pkB;
                #pragma unroll
                for (int j = 0; j < 4; j++){
                    pkA[j] = f2bf(ovA[g*4 + j] * rA);
                    pkB[j] = f2bf(ovB[g*4 + j] * rB);
                }
                *(ushort4v*)(dstA + d) = pkA;
                *(ushort4v*)(dstB + d) = pkB;
            }
        }
    }
}

// ---------------------------------------------------------------- launch
extern "C" void kernel_launch(void* const* d_in, const int* in_sizes, int n_in,
                              void* d_out, int out_size, void* d_ws, size_t ws_size,
                              hipStream_t stream) {
    const float* q    = (const float*)d_in[0];
    const float* gn_w = (const float*)d_in[1];
    const float* gn_b = (const float*)d_in[2];
    const float* wq   = (const float*)d_in[3];
    const float* bq   = (const float*)d_in[4];
    const float* wk   = (const float*)d_in[5];
    const float* bk   = (const float*)d_in[6];
    const float* wv   = (const float*)d_in[7];
    const float* bv   = (const float*)d_in[8];
    const float* wo   = (const float*)d_in[9];
    const float* bo   = (const float*)d_in[10];
    float* outp = (float*)d_out;

    char* ws = (char*)d_ws;
    float2v* parts = (float2v*)ws;                 // 512 x float2 = 4 KB
    unsigned short* xn  = (unsigned short*)(ws + 8192);
    const size_t TOK = (size_t)8192 * 512;
    unsigned short* wqkb = xn + TOK;               // 1024 x 512
    unsigned short* wvb  = wqkb + 1024*512;
    unsigned short* wob  = wvb + 512*512;
    unsigned short* Qb   = wob + 512*512;
    unsigned short* Kb   = Qb + TOK;
    unsigned short* Vt   = Kb + TOK;
    unsigned short* Ob   = Vt + TOK;

    gn_stats_wconv<<<1536, 256, 0, stream>>>(q, parts, wq, wk, wv, wo, wqkb, wvb, wob);
    gn_apply<<<dim3(64, 8, 2), 256, 0, stream>>>(q, parts, gn_w, gn_b, xn);
    gemm_qkv<<<1024, 256, 0, stream>>>(xn, wqkb, wvb, bq, bk, bv, Qb, Kb, Vt);
    attn10<<<1024, 128, 0, stream>>>(Qb, Kb, Vt, Ob);
    gemm_o2<<<dim3(64, 8), 256, 0, stream>>>(wob, Ob, bo, q, outp);
}

// Round 13
// 133.931 us; speedup vs baseline: 1.2841x; 1.2841x over previous
//
#include <hip/hip_runtime.h>
#include <hip/hip_bf16.h>
#include <cstdint>
#include <cstddef>

using bf16x8   = __attribute__((ext_vector_type(8))) short;
using f32x4    = __attribute__((ext_vector_type(4))) float;
using f32x16   = __attribute__((ext_vector_type(16))) float;
using ushort8  = __attribute__((ext_vector_type(8))) unsigned short;
using ushort4v = __attribute__((ext_vector_type(4))) unsigned short;
using float4v  = __attribute__((ext_vector_type(4))) float;
using float2v  = __attribute__((ext_vector_type(2))) float;

#define MFMA16(a,b,c) __builtin_amdgcn_mfma_f32_16x16x32_bf16((a),(b),(c),0,0,0)
#define MFMA32(a,b,c) __builtin_amdgcn_mfma_f32_32x32x16_bf16((a),(b),(c),0,0,0)

#define QSCALE 0.18033688011112042f   // log2(e)/8

__device__ __forceinline__ unsigned short f2bf(float f){
    union { float f; unsigned u; } v; v.f = f;
    unsigned r = v.u + 0x7FFFu + ((v.u >> 16) & 1u);
    return (unsigned short)(r >> 16);
}

__device__ __forceinline__ int cvtpk(float lo, float hi){
    int r;
    asm volatile("v_cvt_pk_bf16_f32 %0, %1, %2" : "=v"(r) : "v"(lo), "v"(hi));
    return r;
}

#if __has_builtin(__builtin_amdgcn_permlane32_swap)
__device__ __forceinline__ void plswap(int &a, int &b){
    auto r = __builtin_amdgcn_permlane32_swap(a, b, false, false);
    a = r[0]; b = r[1];
}
#else
__device__ __forceinline__ void plswap(int &a, int &b){
    int ta = __shfl_xor(a, 32), tb = __shfl_xor(b, 32);
    bool hi = ((threadIdx.x & 63) >= 32);
    int na = hi ? tb : a;
    int nb = hi ? b  : ta;
    a = na; b = nb;
}
#endif

__device__ __forceinline__ void gload16(const unsigned short* g, unsigned short* l){
    __builtin_amdgcn_global_load_lds(
        (const __attribute__((address_space(1))) void*)g,
        (__attribute__((address_space(3))) void*)l,
        16, 0, 0);
}

// ---------------------------------------------------------------- GN partial stats + wconv merged
__global__ __launch_bounds__(256) void gn_stats_wconv(const float* __restrict__ x,
                                                      float2v* __restrict__ parts,
                                                      const float* __restrict__ w0, const float* __restrict__ w1,
                                                      const float* __restrict__ w2, const float* __restrict__ w3,
                                                      unsigned short* wqk, unsigned short* wv, unsigned short* wo){
    int bid = blockIdx.x;
    if (bid < 512){
        const float4v* p4 = (const float4v*)(x + (size_t)bid * 8192);
        float s = 0.f, ss = 0.f;
        #pragma unroll
        for (int i = 0; i < 8; i++){
            float4v v = p4[i*256 + threadIdx.x];
            s  += v[0]+v[1]+v[2]+v[3];
            ss += v[0]*v[0]+v[1]*v[1]+v[2]*v[2]+v[3]*v[3];
        }
        __shared__ float ls[4], lss[4];
        int lane = threadIdx.x & 63, w = threadIdx.x >> 6;
        #pragma unroll
        for (int o = 32; o > 0; o >>= 1){ s += __shfl_down(s, o); ss += __shfl_down(ss, o); }
        if (lane == 0){ ls[w] = s; lss[w] = ss; }
        __syncthreads();
        if (threadIdx.x == 0){
            float2v p;
            p[0] = ls[0]+ls[1]+ls[2]+ls[3];
            p[1] = lss[0]+lss[1]+lss[2]+lss[3];
            parts[bid] = p;
        }
    } else {
        int i2 = bid - 512;
        int y = i2 >> 8, bx = i2 & 255;
        const float* src; unsigned short* dst; float sc = 1.0f;
        switch (y){
            case 0: src = w0; dst = wqk;          sc = QSCALE; break;
            case 1: src = w1; dst = wqk + 512*512; break;
            case 2: src = w2; dst = wv; break;
            default: src = w3; dst = wo; break;
        }
        int i = (bx*256 + threadIdx.x) * 4;
        float4v v = *(const float4v*)(src + i);
        ushort4v o;
        #pragma unroll
        for (int j = 0; j < 4; j++) o[j] = f2bf(v[j]*sc);
        *(ushort4v*)(dst + i) = o;
    }
}

// normalize + transpose; folds the 8 partials per group inline (deterministic).
__global__ __launch_bounds__(256) void gn_apply(const float* __restrict__ x,
                                                const float2v* __restrict__ parts,
                                                const float* __restrict__ gw,
                                                const float* __restrict__ gb,
                                                unsigned short* __restrict__ xn){
    int b = blockIdx.z, c0 = blockIdx.y * 64, n0 = blockIdx.x * 64;
    __shared__ unsigned short tile[64][68];
    __shared__ float gmean[4], grstd[4];
    if (threadIdx.x < 4){
        int g = b*32 + (c0 >> 4) + threadIdx.x;
        float s = 0.f, ss = 0.f;
        #pragma unroll
        for (int e = 0; e < 8; e++){
            float2v p = parts[g*8 + e];
            s += p[0]; ss += p[1];
        }
        float m = s * (1.f/65536.f);
        float var = ss * (1.f/65536.f) - m*m;
        gmean[threadIdx.x] = m;
        grstd[threadIdx.x] = rsqrtf(var + 1e-5f);
    }
    __syncthreads();
    for (int i = threadIdx.x; i < 64*16; i += 256){
        int row = i >> 4, f4 = i & 15;
        int c = c0 + row;
        int gl = row >> 4;
        float rs = grstd[gl];
        float wgt = gw[c] * rs;
        float bia = gb[c] - gmean[gl] * wgt;
        float4v v = *(const float4v*)(x + ((size_t)(b*512 + c))*4096 + n0 + f4*4);
        ushort4v o;
        #pragma unroll
        for (int j = 0; j < 4; j++) o[j] = f2bf(v[j]*wgt + bia);
        *(ushort4v*)&tile[row][f4*4] = o;
    }
    __syncthreads();
    for (int i = threadIdx.x; i < 64*8; i += 256){
        int nr = i >> 3, c8 = i & 7;
        ushort8 o;
        #pragma unroll
        for (int j = 0; j < 8; j++) o[j] = tile[c8*8 + j][nr];
        *(ushort8*)(xn + ((size_t)(b*4096 + n0 + nr))*512 + c0 + c8*8) = o;
    }
}

// ---------------------------------------------------------------- fused QKV projections
__global__ __launch_bounds__(256) void gemm_qkv(const unsigned short* __restrict__ xn,
                                                const unsigned short* __restrict__ wqk,
                                                const unsigned short* __restrict__ Wv,
                                                const float* __restrict__ bq,
                                                const float* __restrict__ bk,
                                                const float* __restrict__ bv,
                                                unsigned short* __restrict__ Q,
                                                unsigned short* __restrict__ K,
                                                unsigned short* __restrict__ Vt){
    __shared__ unsigned short Al[128*32];
    __shared__ unsigned short Bl[128*32];
    int bid = blockIdx.x;
    int t = threadIdx.x, lane = t & 63, w = t >> 6;
    int wr = w >> 1, wc = w & 1;
    int lr = lane >> 2, lc = lane & 3;

    if (bid < 512){
        int m0 = (bid & 63) * 128, n0 = (bid >> 6) * 128;
        f32x4 acc[4][4] = {};
        const unsigned short* Asrc = xn  + (size_t)(m0 + w*32 + lr)*512 + lc*8;
        const unsigned short* Bsrc = wqk + (size_t)(n0 + w*32 + lr)*512 + lc*8;
        unsigned short* Adst = &Al[(w*32)*32];
        unsigned short* Bdst = &Bl[(w*32)*32];

        for (int ks = 0; ks < 16; ks++){
            gload16(Asrc + ks*32,          Adst);
            gload16(Asrc + ks*32 + 16*512, Adst + 16*32);
            gload16(Bsrc + ks*32,          Bdst);
            gload16(Bsrc + ks*32 + 16*512, Bdst + 16*32);
            asm volatile("s_waitcnt vmcnt(0)" ::: "memory");
            __syncthreads();
            bf16x8 a[4], b[4];
            #pragma unroll
            for (int mi = 0; mi < 4; mi++) a[mi] = *(bf16x8*)&Al[(wr*64 + mi*16 + (lane&15))*32 + (lane>>4)*8];
            #pragma unroll
            for (int ni = 0; ni < 4; ni++) b[ni] = *(bf16x8*)&Bl[(wc*64 + ni*16 + (lane&15))*32 + (lane>>4)*8];
            #pragma unroll
            for (int mi = 0; mi < 4; mi++)
                #pragma unroll
                for (int ni = 0; ni < 4; ni++)
                    acc[mi][ni] = MFMA16(a[mi], b[ni], acc[mi][ni]);
            __syncthreads();
        }

        int cK = n0 >> 9;
        const float* bias = cK ? bk : bq;
        unsigned short* dst0 = cK ? K : Q;
        float bsc = cK ? 1.0f : QSCALE;
        #pragma unroll
        for (int mi = 0; mi < 4; mi++)
            #pragma unroll
            for (int ni = 0; ni < 4; ni++)
                #pragma unroll
                for (int r = 0; r < 4; r++){
                    int mrow = m0 + wr*64 + mi*16 + (lane>>4)*4 + r;
                    int col  = (n0 & 511) + wc*64 + ni*16 + (lane&15);
                    int b_ = mrow >> 12, n = mrow & 4095;
                    int h = col >> 6, d = col & 63;
                    float v = acc[mi][ni][r] + bias[col]*bsc;
                    dst0[(size_t)((b_*8+h)*4096 + n)*64 + d] = f2bf(v);
                }
    } else {
        int i2 = bid - 512;
        int m0 = (i2 >> 6) * 64, n0 = (i2 & 63) * 128;
        f32x4 acc[2][4] = {};
        const unsigned short* Asrc = Wv + (size_t)(m0 + w*16 + lr)*512 + lc*8;
        const unsigned short* Bsrc = xn + (size_t)(n0 + w*32 + lr)*512 + lc*8;
        unsigned short* Adst = &Al[(w*16)*32];
        unsigned short* Bdst = &Bl[(w*32)*32];

        for (int ks = 0; ks < 16; ks++){
            gload16(Asrc + ks*32,          Adst);
            gload16(Bsrc + ks*32,          Bdst);
            gload16(Bsrc + ks*32 + 16*512, Bdst + 16*32);
            asm volatile("s_waitcnt vmcnt(0)" ::: "memory");
            __syncthreads();
            bf16x8 a[2], b[4];
            #pragma unroll
            for (int mi = 0; mi < 2; mi++) a[mi] = *(bf16x8*)&Al[(wr*32 + mi*16 + (lane&15))*32 + (lane>>4)*8];
            #pragma unroll
            for (int ni = 0; ni < 4; ni++) b[ni] = *(bf16x8*)&Bl[(wc*64 + ni*16 + (lane&15))*32 + (lane>>4)*8];
            #pragma unroll
            for (int mi = 0; mi < 2; mi++)
                #pragma unroll
                for (int ni = 0; ni < 4; ni++)
                    acc[mi][ni] = MFMA16(a[mi], b[ni], acc[mi][ni]);
            __syncthreads();
        }
        #pragma unroll
        for (int mi = 0; mi < 2; mi++)
            #pragma unroll
            for (int ni = 0; ni < 4; ni++)
                #pragma unroll
                for (int r = 0; r < 4; r++){
                    int row  = m0 + wr*32 + mi*16 + (lane>>4)*4 + r;
                    int colm = n0 + wc*64 + ni*16 + (lane&15);
                    int b_ = colm >> 12, n = colm & 4095;
                    int h = row >> 6, d = row & 63;
                    float v = acc[mi][ni][r] + bv[row];
                    Vt[(size_t)((b_*8+h)*64 + d)*4096 + n] = f2bf(v);
                }
    }
}

// ---------------------------------------------------------------- output projection + residual
__global__ __launch_bounds__(256) void gemm_o2(const unsigned short* __restrict__ Wo,
                                               const unsigned short* __restrict__ Om,
                                               const float* __restrict__ bo,
                                               const float* __restrict__ resid,
                                               float* __restrict__ outp){
    __shared__ unsigned short Al[64*32];
    __shared__ unsigned short Bl[128*32];
    int t = threadIdx.x, lane = t & 63, w = t >> 6;
    int wr = w >> 1, wc = w & 1;
    int m0 = blockIdx.y * 64, n0 = blockIdx.x * 128;
    int lr = lane >> 2, lc = lane & 3;
    f32x4 acc[2][4] = {};

    const unsigned short* Asrc = Wo + (size_t)(m0 + w*16 + lr)*512 + lc*8;
    const unsigned short* Bsrc = Om + (size_t)(n0 + w*32 + lr)*512 + lc*8;
    unsigned short* Adst = &Al[(w*16)*32];
    unsigned short* Bdst = &Bl[(w*32)*32];

    for (int ks = 0; ks < 16; ks++){
        gload16(Asrc + ks*32,          Adst);
        gload16(Bsrc + ks*32,          Bdst);
        gload16(Bsrc + ks*32 + 16*512, Bdst + 16*32);
        asm volatile("s_waitcnt vmcnt(0)" ::: "memory");
        __syncthreads();
        bf16x8 a[2], b[4];
        #pragma unroll
        for (int mi = 0; mi < 2; mi++) a[mi] = *(bf16x8*)&Al[(wr*32 + mi*16 + (lane&15))*32 + (lane>>4)*8];
        #pragma unroll
        for (int ni = 0; ni < 4; ni++) b[ni] = *(bf16x8*)&Bl[(wc*64 + ni*16 + (lane&15))*32 + (lane>>4)*8];
        #pragma unroll
        for (int mi = 0; mi < 2; mi++)
            #pragma unroll
            for (int ni = 0; ni < 4; ni++)
                acc[mi][ni] = MFMA16(a[mi], b[ni], acc[mi][ni]);
        __syncthreads();
    }
    #pragma unroll
    for (int mi = 0; mi < 2; mi++)
        #pragma unroll
        for (int ni = 0; ni < 4; ni++)
            #pragma unroll
            for (int r = 0; r < 4; r++){
                int row  = m0 + wr*32 + mi*16 + (lane>>4)*4 + r;
                int colm = n0 + wc*64 + ni*16 + (lane&15);
                int b_ = colm >> 12, n = colm & 4095;
                size_t oi = ((size_t)(b_*512 + row))*4096 + n;
                outp[oi] = acc[mi][ni][r] + bo[row] + resid[oi];
            }
}

// ---------------------------------------------------------------- flash attention v9: barrier-free (proven 92.5us)
// 2 waves kv-split; V staged into PER-WAVE kv-banks so all K/V LDS traffic is
// wave-local -> no per-tile barriers; per-wave counted vmcnt(8), 2-tile prefetch.
__global__ __launch_bounds__(128, 2) void attn9(const unsigned short* __restrict__ Q,
                                                const unsigned short* __restrict__ K,
                                                const unsigned short* __restrict__ Vt,
                                                unsigned short* __restrict__ O){
    int bid = blockIdx.x;
    int idx = bid >> 3;
    int bh = ((bid & 7) << 1) | (idx >> 6);
    int qt = idx & 63;
    int t = threadIdx.x, lane = t & 63, w = t >> 6;   // w = kv-half
    int ln = lane & 31, hi = lane >> 5;
    int q0 = qt * 64;

    __shared__ unsigned short Kl[2][64*64];        // [buf][kv 64][d 64]  (wave w owns rows w*32..)
    __shared__ unsigned short Vl[2][2][64*32];     // [buf][wave][d 64][kv 32]  (64B rows)

    const unsigned short* Qb = Q  + (size_t)bh * 4096 * 64;
    const unsigned short* Kb = K  + (size_t)bh * 4096 * 64;
    const unsigned short* Vb = Vt + (size_t)bh * 64 * 4096;

    bf16x8 bqa[4], bqb[4];
    #pragma unroll
    for (int dsub = 0; dsub < 4; dsub++){
        bqa[dsub] = *(const bf16x8*)(Qb + (size_t)(q0 + ln)*64      + dsub*16 + hi*8);
        bqb[dsub] = *(const bf16x8*)(Qb + (size_t)(q0 + 32 + ln)*64 + dsub*16 + hi*8);
    }

    // K staging map (8 rows x 128B per gload16, slot XOR row)
    int srow = lane >> 3;
    int sswz = (lane & 7) ^ srow;
    // V staging map (16 rows x 64B per gload16): d = i*16 + (lane>>2), phys slot = lane&3,
    // logical kv-slot s = p ^ ((d>>1)&3)
    int vdl = lane >> 2;
    int vsl = (lane & 3) ^ ((vdl >> 1) & 3);

    auto stage = [&](int kt){
        int kv0 = kt * 64;
        unsigned short* kdst = &Kl[kt & 1][0];
        #pragma unroll
        for (int i = 0; i < 4; i++){
            int r0 = w*32 + i*8;
            gload16(Kb + (size_t)(kv0 + r0 + srow)*64 + sswz*8, kdst + r0*64);
        }
        unsigned short* vdst = &Vl[kt & 1][w][0];
        #pragma unroll
        for (int i = 0; i < 4; i++)
            gload16(Vb + (size_t)(i*16 + vdl)*4096 + kv0 + w*32 + vsl*8, vdst + i*512);
    };

    stage(0);
    stage(1);

    f32x16 o0a, o1a, o0b, o1b, z;
    #pragma unroll
    for (int r = 0; r < 16; r++){ o0a[r]=0.f; o1a[r]=0.f; o0b[r]=0.f; o1b[r]=0.f; z[r]=0.f; }
    float lsA = 0.f, lsB = 0.f;

    const char* KbA = (const char*)&Kl[0][0] + (w*32 + ln)*128;
    int swzr = (ln & 7) << 4;
    const char* VbW = (const char*)&Vl[0][w][0];
    int vrswz = (ln >> 1) & 3;   // same for d=ln and d=32+ln

    for (int kt = 0; kt < 64; kt++){
        if (kt < 63) asm volatile("s_waitcnt vmcnt(8)" ::: "memory");
        else         asm volatile("s_waitcnt vmcnt(0)" ::: "memory");
        __builtin_amdgcn_sched_barrier(0);

        int kboff = (kt & 1) * (64*64*2);
        int vboff = (kt & 1) * (2*64*32*2);

        // ---- QK^T (swapped), wave-local K rows
        f32x16 sA, sB;
        {
            int cb = (hi*16) ^ swzr;
            bf16x8 ak = *(const bf16x8*)(KbA + kboff + cb);
            sA = MFMA32(ak, bqa[0], z);
            sB = MFMA32(ak, bqb[0], z);
        }
        __builtin_amdgcn_s_setprio(1);
        #pragma unroll
        for (int dsub = 1; dsub < 4; dsub++){
            int cb = (dsub*32 + hi*16) ^ swzr;
            bf16x8 ak = *(const bf16x8*)(KbA + kboff + cb);
            sA = MFMA32(ak, bqa[dsub], sA);
            sB = MFMA32(ak, bqb[dsub], sB);
        }
        __builtin_amdgcn_s_setprio(0);

        // ---- p = exp2(s); row-sums
        #pragma unroll
        for (int r = 0; r < 16; r++){ sA[r] = __builtin_amdgcn_exp2f(sA[r]); lsA += sA[r]; }
        #pragma unroll
        for (int r = 0; r < 16; r++){ sB[r] = __builtin_amdgcn_exp2f(sB[r]); lsB += sB[r]; }

        // ---- PV (swapped), wave-local V bank
        __builtin_amdgcn_s_setprio(1);
        #pragma unroll
        for (int hsel = 0; hsel < 2; hsel++){
            int obp = hsel * 8;
            int a0 = cvtpk(sA[obp+0], sA[obp+1]);
            int a1 = cvtpk(sA[obp+2], sA[obp+3]);
            int c0 = cvtpk(sA[obp+4], sA[obp+5]);
            int c1 = cvtpk(sA[obp+6], sA[obp+7]);
            plswap(a0, c0);
            plswap(a1, c1);
            union { int i[4]; bf16x8 v; } fuA;
            fuA.i[0] = a0; fuA.i[1] = a1; fuA.i[2] = c0; fuA.i[3] = c1;

            int d0 = cvtpk(sB[obp+0], sB[obp+1]);
            int d1 = cvtpk(sB[obp+2], sB[obp+3]);
            int e0 = cvtpk(sB[obp+4], sB[obp+5]);
            int e1 = cvtpk(sB[obp+6], sB[obp+7]);
            plswap(d0, e0);
            plswap(d1, e1);
            union { int i[4]; bf16x8 v; } fuB;
            fuB.i[0] = d0; fuB.i[1] = d1; fuB.i[2] = e0; fuB.i[3] = e1;

            int p0 = (((hsel*2 + hi) ^ vrswz) << 4);
            bf16x8 av0 = *(const bf16x8*)(VbW + vboff + ln*64 + p0);
            bf16x8 av1 = *(const bf16x8*)(VbW + vboff + (32 + ln)*64 + p0);
            o0a = MFMA32(av0, fuA.v, o0a);
            o1a = MFMA32(av1, fuA.v, o1a);
            o0b = MFMA32(av0, fuB.v, o0b);
            o1b = MFMA32(av1, fuB.v, o1b);
        }
        __builtin_amdgcn_s_setprio(0);

        __builtin_amdgcn_sched_barrier(0);
        if (kt < 62) stage(kt + 2);
        __builtin_amdgcn_sched_barrier(0);
    }

    // ---- merge kv-halves via LDS, normalize, store
    lsA += __shfl_xor(lsA, 32);
    lsB += __shfl_xor(lsB, 32);
    __syncthreads();
    float* m1 = (float*)&Kl[0][0];
    float* m2 = (float*)&Vl[0][0][0];
    if (w == 1){
        #pragma unroll
        for (int r = 0; r < 16; r++){
            m1[r*64 + lane]        = o0a[r];
            m1[1024 + r*64 + lane] = o1a[r];
            m2[r*64 + lane]        = o0b[r];
            m2[1024 + r*64 + lane] = o1b[r];
        }
        if (hi == 0){ m2[2048 + ln] = lsA; m2[2048 + 32 + ln] = lsB; }
    }
    __syncthreads();
    if (w == 0){
        #pragma unroll
        for (int r = 0; r < 16; r++){
            o0a[r] += m1[r*64 + lane];
            o1a[r] += m1[1024 + r*64 + lane];
            o0b[r] += m2[r*64 + lane];
            o1b[r] += m2[1024 + r*64 + lane];
        }
        float rA = 1.0f / (lsA + m2[2048 + ln]);
        float rB = 1.0f / (lsB + m2[2048 + 32 + ln]);
        int b = bh >> 3, h = bh & 7;
        unsigned short* dstA = O + (size_t)(b*4096 + q0 + ln)*512      + h*64;
        unsigned short* dstB = O + (size_t)(b*4096 + q0 + 32 + ln)*512 + h*64;
        #pragma unroll
        for (int m = 0; m < 2; m++){
            const f32x16& ovA = m ? o1a : o0a;
            const f32x16& ovB = m ? o1b : o0b;
            #pragma unroll
            for (int g = 0; g < 4; g++){
                int d = m*32 + g*8 + hi*4;
                ushort4v pkA, pkB;
                #pragma unroll
                for (int j = 0; j < 4; j++){
                    pkA[j] = f2bf(ovA[g*4 + j] * rA);
                    pkB[j] = f2bf(ovB[g*4 + j] * rB);
                }
                *(ushort4v*)(dstA + d) = pkA;
                *(ushort4v*)(dstB + d) = pkB;
            }
        }
    }
}

// ---------------------------------------------------------------- launch
extern "C" void kernel_launch(void* const* d_in, const int* in_sizes, int n_in,
                              void* d_out, int out_size, void* d_ws, size_t ws_size,
                              hipStream_t stream) {
    const float* q    = (const float*)d_in[0];
    const float* gn_w = (const float*)d_in[1];
    const float* gn_b = (const float*)d_in[2];
    const float* wq   = (const float*)d_in[3];
    const float* bq   = (const float*)d_in[4];
    const float* wk   = (const float*)d_in[5];
    const float* bk   = (const float*)d_in[6];
    const float* wv   = (const float*)d_in[7];
    const float* bv   = (const float*)d_in[8];
    const float* wo   = (const float*)d_in[9];
    const float* bo   = (const float*)d_in[10];
    float* outp = (float*)d_out;

    char* ws = (char*)d_ws;
    float2v* parts = (float2v*)ws;                 // 512 x float2 = 4 KB
    unsigned short* xn  = (unsigned short*)(ws + 8192);
    const size_t TOK = (size_t)8192 * 512;
    unsigned short* wqkb = xn + TOK;               // 1024 x 512
    unsigned short* wvb  = wqkb + 1024*512;
    unsigned short* wob  = wvb + 512*512;
    unsigned short* Qb   = wob + 512*512;
    unsigned short* Kb   = Qb + TOK;
    unsigned short* Vt   = Kb + TOK;
    unsigned short* Ob   = Vt + TOK;

    gn_stats_wconv<<<1536, 256, 0, stream>>>(q, parts, wq, wk, wv, wo, wqkb, wvb, wob);
    gn_apply<<<dim3(64, 8, 2), 256, 0, stream>>>(q, parts, gn_w, gn_b, xn);
    gemm_qkv<<<1024, 256, 0, stream>>>(xn, wqkb, wvb, bq, bk, bv, Qb, Kb, Vt);
    attn9<<<1024, 128, 0, stream>>>(Qb, Kb, Vt, Ob);
    gemm_o2<<<dim3(64, 8), 256, 0, stream>>>(wob, Ob, bo, q, outp);
}

// Round 14
// 133.553 us; speedup vs baseline: 1.2877x; 1.0028x over previous
//
#include <hip/hip_runtime.h>
#include <hip/hip_bf16.h>
#include <cstdint>
#include <cstddef>

using bf16x8   = __attribute__((ext_vector_type(8))) short;
using f32x4    = __attribute__((ext_vector_type(4))) float;
using f32x16   = __attribute__((ext_vector_type(16))) float;
using ushort8  = __attribute__((ext_vector_type(8))) unsigned short;
using ushort4v = __attribute__((ext_vector_type(4))) unsigned short;
using float4v  = __attribute__((ext_vector_type(4))) float;
using float2v  = __attribute__((ext_vector_type(2))) float;

#define MFMA16(a,b,c) __builtin_amdgcn_mfma_f32_16x16x32_bf16((a),(b),(c),0,0,0)
#define MFMA32(a,b,c) __builtin_amdgcn_mfma_f32_32x32x16_bf16((a),(b),(c),0,0,0)

#define QSCALE 0.18033688011112042f   // log2(e)/8

__device__ __forceinline__ unsigned short f2bf(float f){
    union { float f; unsigned u; } v; v.f = f;
    unsigned r = v.u + 0x7FFFu + ((v.u >> 16) & 1u);
    return (unsigned short)(r >> 16);
}

__device__ __forceinline__ int cvtpk(float lo, float hi){
    int r;
    asm volatile("v_cvt_pk_bf16_f32 %0, %1, %2" : "=v"(r) : "v"(lo), "v"(hi));
    return r;
}

#if __has_builtin(__builtin_amdgcn_permlane32_swap)
__device__ __forceinline__ void plswap(int &a, int &b){
    auto r = __builtin_amdgcn_permlane32_swap(a, b, false, false);
    a = r[0]; b = r[1];
}
#else
__device__ __forceinline__ void plswap(int &a, int &b){
    int ta = __shfl_xor(a, 32), tb = __shfl_xor(b, 32);
    bool hi = ((threadIdx.x & 63) >= 32);
    int na = hi ? tb : a;
    int nb = hi ? b  : ta;
    a = na; b = nb;
}
#endif

__device__ __forceinline__ void gload16(const unsigned short* g, unsigned short* l){
    __builtin_amdgcn_global_load_lds(
        (const __attribute__((address_space(1))) void*)g,
        (__attribute__((address_space(3))) void*)l,
        16, 0, 0);
}

// ---------------------------------------------------------------- GN partial stats + wconv merged
__global__ __launch_bounds__(256) void gn_stats_wconv(const float* __restrict__ x,
                                                      float2v* __restrict__ parts,
                                                      const float* __restrict__ w0, const float* __restrict__ w1,
                                                      const float* __restrict__ w2, const float* __restrict__ w3,
                                                      unsigned short* wqk, unsigned short* wv, unsigned short* wo){
    int bid = blockIdx.x;
    if (bid < 512){
        const float4v* p4 = (const float4v*)(x + (size_t)bid * 8192);
        float s = 0.f, ss = 0.f;
        #pragma unroll
        for (int i = 0; i < 8; i++){
            float4v v = p4[i*256 + threadIdx.x];
            s  += v[0]+v[1]+v[2]+v[3];
            ss += v[0]*v[0]+v[1]*v[1]+v[2]*v[2]+v[3]*v[3];
        }
        __shared__ float ls[4], lss[4];
        int lane = threadIdx.x & 63, w = threadIdx.x >> 6;
        #pragma unroll
        for (int o = 32; o > 0; o >>= 1){ s += __shfl_down(s, o); ss += __shfl_down(ss, o); }
        if (lane == 0){ ls[w] = s; lss[w] = ss; }
        __syncthreads();
        if (threadIdx.x == 0){
            float2v p;
            p[0] = ls[0]+ls[1]+ls[2]+ls[3];
            p[1] = lss[0]+lss[1]+lss[2]+lss[3];
            parts[bid] = p;
        }
    } else {
        int i2 = bid - 512;
        int y = i2 >> 8, bx = i2 & 255;
        const float* src; unsigned short* dst; float sc = 1.0f;
        switch (y){
            case 0: src = w0; dst = wqk;          sc = QSCALE; break;
            case 1: src = w1; dst = wqk + 512*512; break;
            case 2: src = w2; dst = wv; break;
            default: src = w3; dst = wo; break;
        }
        int i = (bx*256 + threadIdx.x) * 4;
        float4v v = *(const float4v*)(src + i);
        ushort4v o;
        #pragma unroll
        for (int j = 0; j < 4; j++) o[j] = f2bf(v[j]*sc);
        *(ushort4v*)(dst + i) = o;
    }
}

// normalize + transpose; folds the 8 partials per group inline (deterministic).
__global__ __launch_bounds__(256) void gn_apply(const float* __restrict__ x,
                                                const float2v* __restrict__ parts,
                                                const float* __restrict__ gw,
                                                const float* __restrict__ gb,
                                                unsigned short* __restrict__ xn){
    int b = blockIdx.z, c0 = blockIdx.y * 64, n0 = blockIdx.x * 64;
    __shared__ unsigned short tile[64][68];
    __shared__ float gmean[4], grstd[4];
    if (threadIdx.x < 4){
        int g = b*32 + (c0 >> 4) + threadIdx.x;
        float s = 0.f, ss = 0.f;
        #pragma unroll
        for (int e = 0; e < 8; e++){
            float2v p = parts[g*8 + e];
            s += p[0]; ss += p[1];
        }
        float m = s * (1.f/65536.f);
        float var = ss * (1.f/65536.f) - m*m;
        gmean[threadIdx.x] = m;
        grstd[threadIdx.x] = rsqrtf(var + 1e-5f);
    }
    __syncthreads();
    for (int i = threadIdx.x; i < 64*16; i += 256){
        int row = i >> 4, f4 = i & 15;
        int c = c0 + row;
        int gl = row >> 4;
        float rs = grstd[gl];
        float wgt = gw[c] * rs;
        float bia = gb[c] - gmean[gl] * wgt;
        float4v v = *(const float4v*)(x + ((size_t)(b*512 + c))*4096 + n0 + f4*4);
        ushort4v o;
        #pragma unroll
        for (int j = 0; j < 4; j++) o[j] = f2bf(v[j]*wgt + bia);
        *(ushort4v*)&tile[row][f4*4] = o;
    }
    __syncthreads();
    for (int i = threadIdx.x; i < 64*8; i += 256){
        int nr = i >> 3, c8 = i & 7;
        ushort8 o;
        #pragma unroll
        for (int j = 0; j < 8; j++) o[j] = tile[c8*8 + j][nr];
        *(ushort8*)(xn + ((size_t)(b*4096 + n0 + nr))*512 + c0 + c8*8) = o;
    }
}

// ---------------------------------------------------------------- fused QKV projections
__global__ __launch_bounds__(256) void gemm_qkv(const unsigned short* __restrict__ xn,
                                                const unsigned short* __restrict__ wqk,
                                                const unsigned short* __restrict__ Wv,
                                                const float* __restrict__ bq,
                                                const float* __restrict__ bk,
                                                const float* __restrict__ bv,
                                                unsigned short* __restrict__ Q,
                                                unsigned short* __restrict__ K,
                                                unsigned short* __restrict__ Vt){
    __shared__ unsigned short Al[128*32];
    __shared__ unsigned short Bl[128*32];
    int bid = blockIdx.x;
    int t = threadIdx.x, lane = t & 63, w = t >> 6;
    int wr = w >> 1, wc = w & 1;
    int lr = lane >> 2, lc = lane & 3;

    if (bid < 512){
        int m0 = (bid & 63) * 128, n0 = (bid >> 6) * 128;
        f32x4 acc[4][4] = {};
        const unsigned short* Asrc = xn  + (size_t)(m0 + w*32 + lr)*512 + lc*8;
        const unsigned short* Bsrc = wqk + (size_t)(n0 + w*32 + lr)*512 + lc*8;
        unsigned short* Adst = &Al[(w*32)*32];
        unsigned short* Bdst = &Bl[(w*32)*32];

        for (int ks = 0; ks < 16; ks++){
            gload16(Asrc + ks*32,          Adst);
            gload16(Asrc + ks*32 + 16*512, Adst + 16*32);
            gload16(Bsrc + ks*32,          Bdst);
            gload16(Bsrc + ks*32 + 16*512, Bdst + 16*32);
            asm volatile("s_waitcnt vmcnt(0)" ::: "memory");
            __syncthreads();
            bf16x8 a[4], b[4];
            #pragma unroll
            for (int mi = 0; mi < 4; mi++) a[mi] = *(bf16x8*)&Al[(wr*64 + mi*16 + (lane&15))*32 + (lane>>4)*8];
            #pragma unroll
            for (int ni = 0; ni < 4; ni++) b[ni] = *(bf16x8*)&Bl[(wc*64 + ni*16 + (lane&15))*32 + (lane>>4)*8];
            #pragma unroll
            for (int mi = 0; mi < 4; mi++)
                #pragma unroll
                for (int ni = 0; ni < 4; ni++)
                    acc[mi][ni] = MFMA16(a[mi], b[ni], acc[mi][ni]);
            __syncthreads();
        }

        int cK = n0 >> 9;
        const float* bias = cK ? bk : bq;
        unsigned short* dst0 = cK ? K : Q;
        float bsc = cK ? 1.0f : QSCALE;
        #pragma unroll
        for (int mi = 0; mi < 4; mi++)
            #pragma unroll
            for (int ni = 0; ni < 4; ni++)
                #pragma unroll
                for (int r = 0; r < 4; r++){
                    int mrow = m0 + wr*64 + mi*16 + (lane>>4)*4 + r;
                    int col  = (n0 & 511) + wc*64 + ni*16 + (lane&15);
                    int b_ = mrow >> 12, n = mrow & 4095;
                    int h = col >> 6, d = col & 63;
                    float v = acc[mi][ni][r] + bias[col]*bsc;
                    dst0[(size_t)((b_*8+h)*4096 + n)*64 + d] = f2bf(v);
                }
    } else {
        int i2 = bid - 512;
        int m0 = (i2 >> 6) * 64, n0 = (i2 & 63) * 128;
        f32x4 acc[2][4] = {};
        const unsigned short* Asrc = Wv + (size_t)(m0 + w*16 + lr)*512 + lc*8;
        const unsigned short* Bsrc = xn + (size_t)(n0 + w*32 + lr)*512 + lc*8;
        unsigned short* Adst = &Al[(w*16)*32];
        unsigned short* Bdst = &Bl[(w*32)*32];

        for (int ks = 0; ks < 16; ks++){
            gload16(Asrc + ks*32,          Adst);
            gload16(Bsrc + ks*32,          Bdst);
            gload16(Bsrc + ks*32 + 16*512, Bdst + 16*32);
            asm volatile("s_waitcnt vmcnt(0)" ::: "memory");
            __syncthreads();
            bf16x8 a[2], b[4];
            #pragma unroll
            for (int mi = 0; mi < 2; mi++) a[mi] = *(bf16x8*)&Al[(wr*32 + mi*16 + (lane&15))*32 + (lane>>4)*8];
            #pragma unroll
            for (int ni = 0; ni < 4; ni++) b[ni] = *(bf16x8*)&Bl[(wc*64 + ni*16 + (lane&15))*32 + (lane>>4)*8];
            #pragma unroll
            for (int mi = 0; mi < 2; mi++)
                #pragma unroll
                for (int ni = 0; ni < 4; ni++)
                    acc[mi][ni] = MFMA16(a[mi], b[ni], acc[mi][ni]);
            __syncthreads();
        }
        #pragma unroll
        for (int mi = 0; mi < 2; mi++)
            #pragma unroll
            for (int ni = 0; ni < 4; ni++)
                #pragma unroll
                for (int r = 0; r < 4; r++){
                    int row  = m0 + wr*32 + mi*16 + (lane>>4)*4 + r;
                    int colm = n0 + wc*64 + ni*16 + (lane&15);
                    int b_ = colm >> 12, n = colm & 4095;
                    int h = row >> 6, d = row & 63;
                    float v = acc[mi][ni][r] + bv[row];
                    Vt[(size_t)((b_*8+h)*64 + d)*4096 + n] = f2bf(v);
                }
    }
}

// ---------------------------------------------------------------- output projection + residual
__global__ __launch_bounds__(256) void gemm_o2(const unsigned short* __restrict__ Wo,
                                               const unsigned short* __restrict__ Om,
                                               const float* __restrict__ bo,
                                               const float* __restrict__ resid,
                                               float* __restrict__ outp){
    __shared__ unsigned short Al[64*32];
    __shared__ unsigned short Bl[128*32];
    int t = threadIdx.x, lane = t & 63, w = t >> 6;
    int wr = w >> 1, wc = w & 1;
    int m0 = blockIdx.y * 64, n0 = blockIdx.x * 128;
    int lr = lane >> 2, lc = lane & 3;
    f32x4 acc[2][4] = {};

    const unsigned short* Asrc = Wo + (size_t)(m0 + w*16 + lr)*512 + lc*8;
    const unsigned short* Bsrc = Om + (size_t)(n0 + w*32 + lr)*512 + lc*8;
    unsigned short* Adst = &Al[(w*16)*32];
    unsigned short* Bdst = &Bl[(w*32)*32];

    for (int ks = 0; ks < 16; ks++){
        gload16(Asrc + ks*32,          Adst);
        gload16(Bsrc + ks*32,          Bdst);
        gload16(Bsrc + ks*32 + 16*512, Bdst + 16*32);
        asm volatile("s_waitcnt vmcnt(0)" ::: "memory");
        __syncthreads();
        bf16x8 a[2], b[4];
        #pragma unroll
        for (int mi = 0; mi < 2; mi++) a[mi] = *(bf16x8*)&Al[(wr*32 + mi*16 + (lane&15))*32 + (lane>>4)*8];
        #pragma unroll
        for (int ni = 0; ni < 4; ni++) b[ni] = *(bf16x8*)&Bl[(wc*64 + ni*16 + (lane&15))*32 + (lane>>4)*8];
        #pragma unroll
        for (int mi = 0; mi < 2; mi++)
            #pragma unroll
            for (int ni = 0; ni < 4; ni++)
                acc[mi][ni] = MFMA16(a[mi], b[ni], acc[mi][ni]);
        __syncthreads();
    }
    #pragma unroll
    for (int mi = 0; mi < 2; mi++)
        #pragma unroll
        for (int ni = 0; ni < 4; ni++)
            #pragma unroll
            for (int r = 0; r < 4; r++){
                int row  = m0 + wr*32 + mi*16 + (lane>>4)*4 + r;
                int colm = n0 + wc*64 + ni*16 + (lane&15);
                int b_ = colm >> 12, n = colm & 4095;
                size_t oi = ((size_t)(b_*512 + row))*4096 + n;
                outp[oi] = acc[mi][ni][r] + bo[row] + resid[oi];
            }
}

// ---------------------------------------------------------------- flash attention v11: attn9 + 2-tile pipeline
// Barrier-free wave-local structure (attn9) with software pipelining: at tile t,
// QK(t) MFMAs issue first, then FINISH(t-1) (exp2/pack/PV of the previous tile)
// runs on VALU/LDS while the MFMA pipe is busy. FIFO: prologue [K0,V0,K1];
// per step: vmcnt(8) -> QK(t) -> FINISH(t-1) -> issue [V(t+1), K(t+2)].
__global__ __launch_bounds__(128, 2) void attn11(const unsigned short* __restrict__ Q,
                                                 const unsigned short* __restrict__ K,
                                                 const unsigned short* __restrict__ Vt,
                                                 unsigned short* __restrict__ O){
    int bid = blockIdx.x;
    int idx = bid >> 3;
    int bh = ((bid & 7) << 1) | (idx >> 6);
    int qt = idx & 63;
    int t = threadIdx.x, lane = t & 63, w = t >> 6;   // w = kv-half
    int ln = lane & 31, hi = lane >> 5;
    int q0 = qt * 64;

    __shared__ unsigned short Kl[2][64*64];        // [buf][kv 64][d 64]  (wave w owns rows w*32..)
    __shared__ unsigned short Vl[2][2][64*32];     // [buf][wave][d 64][kv 32]  (64B rows)

    const unsigned short* Qb = Q  + (size_t)bh * 4096 * 64;
    const unsigned short* Kb = K  + (size_t)bh * 4096 * 64;
    const unsigned short* Vb = Vt + (size_t)bh * 64 * 4096;

    bf16x8 bqa[4], bqb[4];
    #pragma unroll
    for (int dsub = 0; dsub < 4; dsub++){
        bqa[dsub] = *(const bf16x8*)(Qb + (size_t)(q0 + ln)*64      + dsub*16 + hi*8);
        bqb[dsub] = *(const bf16x8*)(Qb + (size_t)(q0 + 32 + ln)*64 + dsub*16 + hi*8);
    }

    int srow = lane >> 3;
    int sswz = (lane & 7) ^ srow;
    int vdl = lane >> 2;
    int vsl = (lane & 3) ^ ((vdl >> 1) & 3);

    auto stageK = [&](int kt){
        int kv0 = kt * 64;
        unsigned short* kdst = &Kl[kt & 1][0];
        #pragma unroll
        for (int i = 0; i < 4; i++){
            int r0 = w*32 + i*8;
            gload16(Kb + (size_t)(kv0 + r0 + srow)*64 + sswz*8, kdst + r0*64);
        }
    };
    auto stageV = [&](int kt){
        int kv0 = kt * 64;
        unsigned short* vdst = &Vl[kt & 1][w][0];
        #pragma unroll
        for (int i = 0; i < 4; i++)
            gload16(Vb + (size_t)(i*16 + vdl)*4096 + kv0 + w*32 + vsl*8, vdst + i*512);
    };

    f32x16 o0a, o1a, o0b, o1b, z, sEA, sEB, sOA, sOB;
    #pragma unroll
    for (int r = 0; r < 16; r++){ o0a[r]=0.f; o1a[r]=0.f; o0b[r]=0.f; o1b[r]=0.f; z[r]=0.f; }
    float lsA = 0.f, lsB = 0.f;

    const char* KbA = (const char*)&Kl[0][0] + (w*32 + ln)*128;
    int swzr = (ln & 7) << 4;
    const char* VbW = (const char*)&Vl[0][w][0];
    int vrswz = (ln >> 1) & 3;
    const int KBUFSZ = 64*64*2;
    const int VBUFSZ = 2*64*32*2;

#define QKSTEP(SA,SB, KBOFF) { \
    { int cb = (hi*16) ^ swzr; \
      bf16x8 ak = *(const bf16x8*)(KbA + (KBOFF) + cb); \
      SA = MFMA32(ak, bqa[0], z); \
      SB = MFMA32(ak, bqb[0], z); } \
    _Pragma("unroll") \
    for (int dsub = 1; dsub < 4; dsub++){ \
        int cb = (dsub*32 + hi*16) ^ swzr; \
        bf16x8 ak = *(const bf16x8*)(KbA + (KBOFF) + cb); \
        SA = MFMA32(ak, bqa[dsub], SA); \
        SB = MFMA32(ak, bqb[dsub], SB); \
    } }

#define FINISH(SA,SB, VBOFF) { \
    _Pragma("unroll") \
    for (int r = 0; r < 16; r++){ SA[r] = __builtin_amdgcn_exp2f(SA[r]); lsA += SA[r]; } \
    _Pragma("unroll") \
    for (int r = 0; r < 16; r++){ SB[r] = __builtin_amdgcn_exp2f(SB[r]); lsB += SB[r]; } \
    _Pragma("unroll") \
    for (int hsel = 0; hsel < 2; hsel++){ \
        int obp = hsel * 8; \
        int a0 = cvtpk(SA[obp+0], SA[obp+1]); \
        int a1 = cvtpk(SA[obp+2], SA[obp+3]); \
        int c0 = cvtpk(SA[obp+4], SA[obp+5]); \
        int c1 = cvtpk(SA[obp+6], SA[obp+7]); \
        plswap(a0, c0); plswap(a1, c1); \
        union { int i[4]; bf16x8 v; } fuA; \
        fuA.i[0] = a0; fuA.i[1] = a1; fuA.i[2] = c0; fuA.i[3] = c1; \
        int d0 = cvtpk(SB[obp+0], SB[obp+1]); \
        int d1 = cvtpk(SB[obp+2], SB[obp+3]); \
        int e0 = cvtpk(SB[obp+4], SB[obp+5]); \
        int e1 = cvtpk(SB[obp+6], SB[obp+7]); \
        plswap(d0, e0); plswap(d1, e1); \
        union { int i[4]; bf16x8 v; } fuB; \
        fuB.i[0] = d0; fuB.i[1] = d1; fuB.i[2] = e0; fuB.i[3] = e1; \
        int p0 = (((hsel*2 + hi) ^ vrswz) << 4); \
        bf16x8 av0 = *(const bf16x8*)(VbW + (VBOFF) + ln*64 + p0); \
        bf16x8 av1 = *(const bf16x8*)(VbW + (VBOFF) + (32 + ln)*64 + p0); \
        o0a = MFMA32(av0, fuA.v, o0a); \
        o1a = MFMA32(av1, fuA.v, o1a); \
        o0b = MFMA32(av0, fuB.v, o0b); \
        o1b = MFMA32(av1, fuB.v, o1b); \
    } }

    // prologue FIFO: [K0, V0, K1] (12 outstanding)
    stageK(0);
    stageV(0);
    stageK(1);

    // step 0 (even): QK(0) only
    asm volatile("s_waitcnt vmcnt(8)" ::: "memory");
    __builtin_amdgcn_sched_barrier(0);
    QKSTEP(sEA, sEB, 0)
    __builtin_amdgcn_sched_barrier(0);
    stageV(1);
    stageK(2);
    __builtin_amdgcn_sched_barrier(0);

    // steady pairs: odd t = 2tt+1 (1..61), even t+1 = 2tt+2 (2..62)
    for (int tt = 0; tt < 31; tt++){
        int t1 = 2*tt + 1;
        // ---- odd step t1: K buf 1; FINISH prev even (V buf 0)
        asm volatile("s_waitcnt vmcnt(8)" ::: "memory");
        __builtin_amdgcn_sched_barrier(0);
        QKSTEP(sOA, sOB, KBUFSZ)
        FINISH(sEA, sEB, 0)
        __builtin_amdgcn_sched_barrier(0);
        stageV(t1 + 1);                 // V(t1+1) -> buf 0
        stageK(t1 + 2);                 // K(t1+2) <= 63 for tt<=30
        __builtin_amdgcn_sched_barrier(0);
        // ---- even step t1+1: K buf 0; FINISH prev odd (V buf 1)
        asm volatile("s_waitcnt vmcnt(8)" ::: "memory");
        __builtin_amdgcn_sched_barrier(0);
        QKSTEP(sEA, sEB, 0)
        FINISH(sOA, sOB, VBUFSZ)
        __builtin_amdgcn_sched_barrier(0);
        stageV(t1 + 2);                 // V(t1+2) <= 63 -> buf 1
        if (tt < 30) stageK(t1 + 3);    // K(2tt+4) <= 63 only for tt<=29
        __builtin_amdgcn_sched_barrier(0);
    }

    // peeled odd step t = 63: no staging
    asm volatile("s_waitcnt vmcnt(4)" ::: "memory");
    __builtin_amdgcn_sched_barrier(0);
    QKSTEP(sOA, sOB, KBUFSZ)
    FINISH(sEA, sEB, 0)                 // tile 62 (V buf 0)
    asm volatile("s_waitcnt vmcnt(0)" ::: "memory");
    __builtin_amdgcn_sched_barrier(0);
    FINISH(sOA, sOB, VBUFSZ)            // tile 63 (V buf 1)

#undef QKSTEP
#undef FINISH

    // ---- merge kv-halves via LDS, normalize, store
    lsA += __shfl_xor(lsA, 32);
    lsB += __shfl_xor(lsB, 32);
    __syncthreads();
    float* m1 = (float*)&Kl[0][0];
    float* m2 = (float*)&Vl[0][0][0];
    if (w == 1){
        #pragma unroll
        for (int r = 0; r < 16; r++){
            m1[r*64 + lane]        = o0a[r];
            m1[1024 + r*64 + lane] = o1a[r];
            m2[r*64 + lane]        = o0b[r];
            m2[1024 + r*64 + lane] = o1b[r];
        }
        if (hi == 0){ m2[2048 + ln] = lsA; m2[2048 + 32 + ln] = lsB; }
    }
    __syncthreads();
    if (w == 0){
        #pragma unroll
        for (int r = 0; r < 16; r++){
            o0a[r] += m1[r*64 + lane];
            o1a[r] += m1[1024 + r*64 + lane];
            o0b[r] += m2[r*64 + lane];
            o1b[r] += m2[1024 + r*64 + lane];
        }
        float rA = 1.0f / (lsA + m2[2048 + ln]);
        float rB = 1.0f / (lsB + m2[2048 + 32 + ln]);
        int b = bh >> 3, h = bh & 7;
        unsigned short* dstA = O + (size_t)(b*4096 + q0 + ln)*512      + h*64;
        unsigned short* dstB = O + (size_t)(b*4096 + q0 + 32 + ln)*512 + h*64;
        #pragma unroll
        for (int m = 0; m < 2; m++){
            const f32x16& ovA = m ? o1a : o0a;
            const f32x16& ovB = m ? o1b : o0b;
            #pragma unroll
            for (int g = 0; g < 4; g++){
                int d = m*32 + g*8 + hi*4;
                ushort4v pkA, pkB;
                #pragma unroll
                for (int j = 0; j < 4; j++){
                    pkA[j] = f2bf(ovA[g*4 + j] * rA);
                    pkB[j] = f2bf(ovB[g*4 + j] * rB);
                }
                *(ushort4v*)(dstA + d) = pkA;
                *(ushort4v*)(dstB + d) = pkB;
            }
        }
    }
}

// ---------------------------------------------------------------- launch
extern "C" void kernel_launch(void* const* d_in, const int* in_sizes, int n_in,
                              void* d_out, int out_size, void* d_ws, size_t ws_size,
                              hipStream_t stream) {
    const float* q    = (const float*)d_in[0];
    const float* gn_w = (const float*)d_in[1];
    const float* gn_b = (const float*)d_in[2];
    const float* wq   = (const float*)d_in[3];
    const float* bq   = (const float*)d_in[4];
    const float* wk   = (const float*)d_in[5];
    const float* bk   = (const float*)d_in[6];
    const float* wv   = (const float*)d_in[7];
    const float* bv   = (const float*)d_in[8];
    const float* wo   = (const float*)d_in[9];
    const float* bo   = (const float*)d_in[10];
    float* outp = (float*)d_out;

    char* ws = (char*)d_ws;
    float2v* parts = (float2v*)ws;                 // 512 x float2 = 4 KB
    unsigned short* xn  = (unsigned short*)(ws + 8192);
    const size_t TOK = (size_t)8192 * 512;
    unsigned short* wqkb = xn + TOK;               // 1024 x 512
    unsigned short* wvb  = wqkb + 1024*512;
    unsigned short* wob  = wvb + 512*512;
    unsigned short* Qb   = wob + 512*512;
    unsigned short* Kb   = Qb + TOK;
    unsigned short* Vt   = Kb + TOK;
    unsigned short* Ob   = Vt + TOK;

    gn_stats_wconv<<<1536, 256, 0, stream>>>(q, parts, wq, wk, wv, wo, wqkb, wvb, wob);
    gn_apply<<<dim3(64, 8, 2), 256, 0, stream>>>(q, parts, gn_w, gn_b, xn);
    gemm_qkv<<<1024, 256, 0, stream>>>(xn, wqkb, wvb, bq, bk, bv, Qb, Kb, Vt);
    attn11<<<1024, 128, 0, stream>>>(Qb, Kb, Vt, Ob);
    gemm_o2<<<dim3(64, 8), 256, 0, stream>>>(wob, Ob, bo, q, outp);
}

// Round 15
// 131.377 us; speedup vs baseline: 1.3090x; 1.0166x over previous
//
#include <hip/hip_runtime.h>
#include <hip/hip_bf16.h>
#include <cstdint>
#include <cstddef>

using bf16x8   = __attribute__((ext_vector_type(8))) short;
using f32x4    = __attribute__((ext_vector_type(4))) float;
using f32x16   = __attribute__((ext_vector_type(16))) float;
using ushort8  = __attribute__((ext_vector_type(8))) unsigned short;
using ushort4v = __attribute__((ext_vector_type(4))) unsigned short;
using float4v  = __attribute__((ext_vector_type(4))) float;
using float2v  = __attribute__((ext_vector_type(2))) float;

#define MFMA16(a,b,c) __builtin_amdgcn_mfma_f32_16x16x32_bf16((a),(b),(c),0,0,0)
#define MFMA32(a,b,c) __builtin_amdgcn_mfma_f32_32x32x16_bf16((a),(b),(c),0,0,0)

#define QSCALE 0.18033688011112042f   // log2(e)/8

__device__ __forceinline__ unsigned short f2bf(float f){
    union { float f; unsigned u; } v; v.f = f;
    unsigned r = v.u + 0x7FFFu + ((v.u >> 16) & 1u);
    return (unsigned short)(r >> 16);
}

__device__ __forceinline__ int cvtpk(float lo, float hi){
    int r;
    asm volatile("v_cvt_pk_bf16_f32 %0, %1, %2" : "=v"(r) : "v"(lo), "v"(hi));
    return r;
}

#if __has_builtin(__builtin_amdgcn_permlane32_swap)
__device__ __forceinline__ void plswap(int &a, int &b){
    auto r = __builtin_amdgcn_permlane32_swap(a, b, false, false);
    a = r[0]; b = r[1];
}
#else
__device__ __forceinline__ void plswap(int &a, int &b){
    int ta = __shfl_xor(a, 32), tb = __shfl_xor(b, 32);
    bool hi = ((threadIdx.x & 63) >= 32);
    int na = hi ? tb : a;
    int nb = hi ? b  : ta;
    a = na; b = nb;
}
#endif

__device__ __forceinline__ void gload16(const unsigned short* g, unsigned short* l){
    __builtin_amdgcn_global_load_lds(
        (const __attribute__((address_space(1))) void*)g,
        (__attribute__((address_space(3))) void*)l,
        16, 0, 0);
}

// ---------------------------------------------------------------- GN partial stats + wconv merged
__global__ __launch_bounds__(256) void gn_stats_wconv(const float* __restrict__ x,
                                                      float2v* __restrict__ parts,
                                                      const float* __restrict__ w0, const float* __restrict__ w1,
                                                      const float* __restrict__ w2, const float* __restrict__ w3,
                                                      unsigned short* wqk, unsigned short* wv, unsigned short* wo){
    int bid = blockIdx.x;
    if (bid < 512){
        const float4v* p4 = (const float4v*)(x + (size_t)bid * 8192);
        float s = 0.f, ss = 0.f;
        #pragma unroll
        for (int i = 0; i < 8; i++){
            float4v v = p4[i*256 + threadIdx.x];
            s  += v[0]+v[1]+v[2]+v[3];
            ss += v[0]*v[0]+v[1]*v[1]+v[2]*v[2]+v[3]*v[3];
        }
        __shared__ float ls[4], lss[4];
        int lane = threadIdx.x & 63, w = threadIdx.x >> 6;
        #pragma unroll
        for (int o = 32; o > 0; o >>= 1){ s += __shfl_down(s, o); ss += __shfl_down(ss, o); }
        if (lane == 0){ ls[w] = s; lss[w] = ss; }
        __syncthreads();
        if (threadIdx.x == 0){
            float2v p;
            p[0] = ls[0]+ls[1]+ls[2]+ls[3];
            p[1] = lss[0]+lss[1]+lss[2]+lss[3];
            parts[bid] = p;
        }
    } else {
        int i2 = bid - 512;
        int y = i2 >> 8, bx = i2 & 255;
        const float* src; unsigned short* dst; float sc = 1.0f;
        switch (y){
            case 0: src = w0; dst = wqk;          sc = QSCALE; break;
            case 1: src = w1; dst = wqk + 512*512; break;
            case 2: src = w2; dst = wv; break;
            default: src = w3; dst = wo; break;
        }
        int i = (bx*256 + threadIdx.x) * 4;
        float4v v = *(const float4v*)(src + i);
        ushort4v o;
        #pragma unroll
        for (int j = 0; j < 4; j++) o[j] = f2bf(v[j]*sc);
        *(ushort4v*)(dst + i) = o;
    }
}

// normalize + transpose; folds the 8 partials per group inline (deterministic).
__global__ __launch_bounds__(256) void gn_apply(const float* __restrict__ x,
                                                const float2v* __restrict__ parts,
                                                const float* __restrict__ gw,
                                                const float* __restrict__ gb,
                                                unsigned short* __restrict__ xn){
    int b = blockIdx.z, c0 = blockIdx.y * 64, n0 = blockIdx.x * 64;
    __shared__ unsigned short tile[64][68];
    __shared__ float gmean[4], grstd[4];
    if (threadIdx.x < 4){
        int g = b*32 + (c0 >> 4) + threadIdx.x;
        float s = 0.f, ss = 0.f;
        #pragma unroll
        for (int e = 0; e < 8; e++){
            float2v p = parts[g*8 + e];
            s += p[0]; ss += p[1];
        }
        float m = s * (1.f/65536.f);
        float var = ss * (1.f/65536.f) - m*m;
        gmean[threadIdx.x] = m;
        grstd[threadIdx.x] = rsqrtf(var + 1e-5f);
    }
    __syncthreads();
    for (int i = threadIdx.x; i < 64*16; i += 256){
        int row = i >> 4, f4 = i & 15;
        int c = c0 + row;
        int gl = row >> 4;
        float rs = grstd[gl];
        float wgt = gw[c] * rs;
        float bia = gb[c] - gmean[gl] * wgt;
        float4v v = *(const float4v*)(x + ((size_t)(b*512 + c))*4096 + n0 + f4*4);
        ushort4v o;
        #pragma unroll
        for (int j = 0; j < 4; j++) o[j] = f2bf(v[j]*wgt + bia);
        *(ushort4v*)&tile[row][f4*4] = o;
    }
    __syncthreads();
    for (int i = threadIdx.x; i < 64*8; i += 256){
        int nr = i >> 3, c8 = i & 7;
        ushort8 o;
        #pragma unroll
        for (int j = 0; j < 8; j++) o[j] = tile[c8*8 + j][nr];
        *(ushort8*)(xn + ((size_t)(b*4096 + n0 + nr))*512 + c0 + c8*8) = o;
    }
}

// ---------------------------------------------------------------- fused QKV projections
__global__ __launch_bounds__(256) void gemm_qkv(const unsigned short* __restrict__ xn,
                                                const unsigned short* __restrict__ wqk,
                                                const unsigned short* __restrict__ Wv,
                                                const float* __restrict__ bq,
                                                const float* __restrict__ bk,
                                                const float* __restrict__ bv,
                                                unsigned short* __restrict__ Q,
                                                unsigned short* __restrict__ K,
                                                unsigned short* __restrict__ Vt){
    __shared__ unsigned short Al[128*32];
    __shared__ unsigned short Bl[128*32];
    int bid = blockIdx.x;
    int t = threadIdx.x, lane = t & 63, w = t >> 6;
    int wr = w >> 1, wc = w & 1;
    int lr = lane >> 2, lc = lane & 3;

    if (bid < 512){
        int m0 = (bid & 63) * 128, n0 = (bid >> 6) * 128;
        f32x4 acc[4][4] = {};
        const unsigned short* Asrc = xn  + (size_t)(m0 + w*32 + lr)*512 + lc*8;
        const unsigned short* Bsrc = wqk + (size_t)(n0 + w*32 + lr)*512 + lc*8;
        unsigned short* Adst = &Al[(w*32)*32];
        unsigned short* Bdst = &Bl[(w*32)*32];

        for (int ks = 0; ks < 16; ks++){
            gload16(Asrc + ks*32,          Adst);
            gload16(Asrc + ks*32 + 16*512, Adst + 16*32);
            gload16(Bsrc + ks*32,          Bdst);
            gload16(Bsrc + ks*32 + 16*512, Bdst + 16*32);
            asm volatile("s_waitcnt vmcnt(0)" ::: "memory");
            __syncthreads();
            bf16x8 a[4], b[4];
            #pragma unroll
            for (int mi = 0; mi < 4; mi++) a[mi] = *(bf16x8*)&Al[(wr*64 + mi*16 + (lane&15))*32 + (lane>>4)*8];
            #pragma unroll
            for (int ni = 0; ni < 4; ni++) b[ni] = *(bf16x8*)&Bl[(wc*64 + ni*16 + (lane&15))*32 + (lane>>4)*8];
            #pragma unroll
            for (int mi = 0; mi < 4; mi++)
                #pragma unroll
                for (int ni = 0; ni < 4; ni++)
                    acc[mi][ni] = MFMA16(a[mi], b[ni], acc[mi][ni]);
            __syncthreads();
        }

        int cK = n0 >> 9;
        const float* bias = cK ? bk : bq;
        unsigned short* dst0 = cK ? K : Q;
        float bsc = cK ? 1.0f : QSCALE;
        #pragma unroll
        for (int mi = 0; mi < 4; mi++)
            #pragma unroll
            for (int ni = 0; ni < 4; ni++)
                #pragma unroll
                for (int r = 0; r < 4; r++){
                    int mrow = m0 + wr*64 + mi*16 + (lane>>4)*4 + r;
                    int col  = (n0 & 511) + wc*64 + ni*16 + (lane&15);
                    int b_ = mrow >> 12, n = mrow & 4095;
                    int h = col >> 6, d = col & 63;
                    float v = acc[mi][ni][r] + bias[col]*bsc;
                    dst0[(size_t)((b_*8+h)*4096 + n)*64 + d] = f2bf(v);
                }
    } else {
        int i2 = bid - 512;
        int m0 = (i2 >> 6) * 64, n0 = (i2 & 63) * 128;
        f32x4 acc[2][4] = {};
        const unsigned short* Asrc = Wv + (size_t)(m0 + w*16 + lr)*512 + lc*8;
        const unsigned short* Bsrc = xn + (size_t)(n0 + w*32 + lr)*512 + lc*8;
        unsigned short* Adst = &Al[(w*16)*32];
        unsigned short* Bdst = &Bl[(w*32)*32];

        for (int ks = 0; ks < 16; ks++){
            gload16(Asrc + ks*32,          Adst);
            gload16(Bsrc + ks*32,          Bdst);
            gload16(Bsrc + ks*32 + 16*512, Bdst + 16*32);
            asm volatile("s_waitcnt vmcnt(0)" ::: "memory");
            __syncthreads();
            bf16x8 a[2], b[4];
            #pragma unroll
            for (int mi = 0; mi < 2; mi++) a[mi] = *(bf16x8*)&Al[(wr*32 + mi*16 + (lane&15))*32 + (lane>>4)*8];
            #pragma unroll
            for (int ni = 0; ni < 4; ni++) b[ni] = *(bf16x8*)&Bl[(wc*64 + ni*16 + (lane&15))*32 + (lane>>4)*8];
            #pragma unroll
            for (int mi = 0; mi < 2; mi++)
                #pragma unroll
                for (int ni = 0; ni < 4; ni++)
                    acc[mi][ni] = MFMA16(a[mi], b[ni], acc[mi][ni]);
            __syncthreads();
        }
        #pragma unroll
        for (int mi = 0; mi < 2; mi++)
            #pragma unroll
            for (int ni = 0; ni < 4; ni++)
                #pragma unroll
                for (int r = 0; r < 4; r++){
                    int row  = m0 + wr*32 + mi*16 + (lane>>4)*4 + r;
                    int colm = n0 + wc*64 + ni*16 + (lane&15);
                    int b_ = colm >> 12, n = colm & 4095;
                    int h = row >> 6, d = row & 63;
                    float v = acc[mi][ni][r] + bv[row];
                    Vt[(size_t)((b_*8+h)*64 + d)*4096 + n] = f2bf(v);
                }
    }
}

// ---------------------------------------------------------------- output projection + residual
__global__ __launch_bounds__(256) void gemm_o2(const unsigned short* __restrict__ Wo,
                                               const unsigned short* __restrict__ Om,
                                               const float* __restrict__ bo,
                                               const float* __restrict__ resid,
                                               float* __restrict__ outp){
    __shared__ unsigned short Al[64*32];
    __shared__ unsigned short Bl[128*32];
    int t = threadIdx.x, lane = t & 63, w = t >> 6;
    int wr = w >> 1, wc = w & 1;
    int m0 = blockIdx.y * 64, n0 = blockIdx.x * 128;
    int lr = lane >> 2, lc = lane & 3;
    f32x4 acc[2][4] = {};

    const unsigned short* Asrc = Wo + (size_t)(m0 + w*16 + lr)*512 + lc*8;
    const unsigned short* Bsrc = Om + (size_t)(n0 + w*32 + lr)*512 + lc*8;
    unsigned short* Adst = &Al[(w*16)*32];
    unsigned short* Bdst = &Bl[(w*32)*32];

    for (int ks = 0; ks < 16; ks++){
        gload16(Asrc + ks*32,          Adst);
        gload16(Bsrc + ks*32,          Bdst);
        gload16(Bsrc + ks*32 + 16*512, Bdst + 16*32);
        asm volatile("s_waitcnt vmcnt(0)" ::: "memory");
        __syncthreads();
        bf16x8 a[2], b[4];
        #pragma unroll
        for (int mi = 0; mi < 2; mi++) a[mi] = *(bf16x8*)&Al[(wr*32 + mi*16 + (lane&15))*32 + (lane>>4)*8];
        #pragma unroll
        for (int ni = 0; ni < 4; ni++) b[ni] = *(bf16x8*)&Bl[(wc*64 + ni*16 + (lane&15))*32 + (lane>>4)*8];
        #pragma unroll
        for (int mi = 0; mi < 2; mi++)
            #pragma unroll
            for (int ni = 0; ni < 4; ni++)
                acc[mi][ni] = MFMA16(a[mi], b[ni], acc[mi][ni]);
        __syncthreads();
    }
    #pragma unroll
    for (int mi = 0; mi < 2; mi++)
        #pragma unroll
        for (int ni = 0; ni < 4; ni++)
            #pragma unroll
            for (int r = 0; r < 4; r++){
                int row  = m0 + wr*32 + mi*16 + (lane>>4)*4 + r;
                int colm = n0 + wc*64 + ni*16 + (lane&15);
                int b_ = colm >> 12, n = colm & 4095;
                size_t oi = ((size_t)(b_*512 + row))*4096 + n;
                outp[oi] = acc[mi][ni][r] + bo[row] + resid[oi];
            }
}

// ---------------------------------------------------------------- flash attention v12: attn11 + parallel l-sums
// Identical pipeline to attn11; the only change is the row-sum accumulation:
// 4-way partial sums break the 16-deep dependent-add chain per tile.
__global__ __launch_bounds__(128, 2) void attn12(const unsigned short* __restrict__ Q,
                                                 const unsigned short* __restrict__ K,
                                                 const unsigned short* __restrict__ Vt,
                                                 unsigned short* __restrict__ O){
    int bid = blockIdx.x;
    int idx = bid >> 3;
    int bh = ((bid & 7) << 1) | (idx >> 6);
    int qt = idx & 63;
    int t = threadIdx.x, lane = t & 63, w = t >> 6;   // w = kv-half
    int ln = lane & 31, hi = lane >> 5;
    int q0 = qt * 64;

    __shared__ unsigned short Kl[2][64*64];        // [buf][kv 64][d 64]  (wave w owns rows w*32..)
    __shared__ unsigned short Vl[2][2][64*32];     // [buf][wave][d 64][kv 32]  (64B rows)

    const unsigned short* Qb = Q  + (size_t)bh * 4096 * 64;
    const unsigned short* Kb = K  + (size_t)bh * 4096 * 64;
    const unsigned short* Vb = Vt + (size_t)bh * 64 * 4096;

    bf16x8 bqa[4], bqb[4];
    #pragma unroll
    for (int dsub = 0; dsub < 4; dsub++){
        bqa[dsub] = *(const bf16x8*)(Qb + (size_t)(q0 + ln)*64      + dsub*16 + hi*8);
        bqb[dsub] = *(const bf16x8*)(Qb + (size_t)(q0 + 32 + ln)*64 + dsub*16 + hi*8);
    }

    int srow = lane >> 3;
    int sswz = (lane & 7) ^ srow;
    int vdl = lane >> 2;
    int vsl = (lane & 3) ^ ((vdl >> 1) & 3);

    auto stageK = [&](int kt){
        int kv0 = kt * 64;
        unsigned short* kdst = &Kl[kt & 1][0];
        #pragma unroll
        for (int i = 0; i < 4; i++){
            int r0 = w*32 + i*8;
            gload16(Kb + (size_t)(kv0 + r0 + srow)*64 + sswz*8, kdst + r0*64);
        }
    };
    auto stageV = [&](int kt){
        int kv0 = kt * 64;
        unsigned short* vdst = &Vl[kt & 1][w][0];
        #pragma unroll
        for (int i = 0; i < 4; i++)
            gload16(Vb + (size_t)(i*16 + vdl)*4096 + kv0 + w*32 + vsl*8, vdst + i*512);
    };

    f32x16 o0a, o1a, o0b, o1b, z, sEA, sEB, sOA, sOB;
    #pragma unroll
    for (int r = 0; r < 16; r++){ o0a[r]=0.f; o1a[r]=0.f; o0b[r]=0.f; o1b[r]=0.f; z[r]=0.f; }
    f32x4 lpA = {0.f,0.f,0.f,0.f}, lpB = {0.f,0.f,0.f,0.f};

    const char* KbA = (const char*)&Kl[0][0] + (w*32 + ln)*128;
    int swzr = (ln & 7) << 4;
    const char* VbW = (const char*)&Vl[0][w][0];
    int vrswz = (ln >> 1) & 3;
    const int KBUFSZ = 64*64*2;
    const int VBUFSZ = 2*64*32*2;

#define QKSTEP(SA,SB, KBOFF) { \
    { int cb = (hi*16) ^ swzr; \
      bf16x8 ak = *(const bf16x8*)(KbA + (KBOFF) + cb); \
      SA = MFMA32(ak, bqa[0], z); \
      SB = MFMA32(ak, bqb[0], z); } \
    _Pragma("unroll") \
    for (int dsub = 1; dsub < 4; dsub++){ \
        int cb = (dsub*32 + hi*16) ^ swzr; \
        bf16x8 ak = *(const bf16x8*)(KbA + (KBOFF) + cb); \
        SA = MFMA32(ak, bqa[dsub], SA); \
        SB = MFMA32(ak, bqb[dsub], SB); \
    } }

#define FINISH(SA,SB, VBOFF) { \
    _Pragma("unroll") \
    for (int r = 0; r < 4; r++){ \
        _Pragma("unroll") \
        for (int j = 0; j < 4; j++){ \
            SA[4*r+j] = __builtin_amdgcn_exp2f(SA[4*r+j]); lpA[j] += SA[4*r+j]; \
        } \
    } \
    _Pragma("unroll") \
    for (int r = 0; r < 4; r++){ \
        _Pragma("unroll") \
        for (int j = 0; j < 4; j++){ \
            SB[4*r+j] = __builtin_amdgcn_exp2f(SB[4*r+j]); lpB[j] += SB[4*r+j]; \
        } \
    } \
    _Pragma("unroll") \
    for (int hsel = 0; hsel < 2; hsel++){ \
        int obp = hsel * 8; \
        int a0 = cvtpk(SA[obp+0], SA[obp+1]); \
        int a1 = cvtpk(SA[obp+2], SA[obp+3]); \
        int c0 = cvtpk(SA[obp+4], SA[obp+5]); \
        int c1 = cvtpk(SA[obp+6], SA[obp+7]); \
        plswap(a0, c0); plswap(a1, c1); \
        union { int i[4]; bf16x8 v; } fuA; \
        fuA.i[0] = a0; fuA.i[1] = a1; fuA.i[2] = c0; fuA.i[3] = c1; \
        int d0 = cvtpk(SB[obp+0], SB[obp+1]); \
        int d1 = cvtpk(SB[obp+2], SB[obp+3]); \
        int e0 = cvtpk(SB[obp+4], SB[obp+5]); \
        int e1 = cvtpk(SB[obp+6], SB[obp+7]); \
        plswap(d0, e0); plswap(d1, e1); \
        union { int i[4]; bf16x8 v; } fuB; \
        fuB.i[0] = d0; fuB.i[1] = d1; fuB.i[2] = e0; fuB.i[3] = e1; \
        int p0 = (((hsel*2 + hi) ^ vrswz) << 4); \
        bf16x8 av0 = *(const bf16x8*)(VbW + (VBOFF) + ln*64 + p0); \
        bf16x8 av1 = *(const bf16x8*)(VbW + (VBOFF) + (32 + ln)*64 + p0); \
        o0a = MFMA32(av0, fuA.v, o0a); \
        o1a = MFMA32(av1, fuA.v, o1a); \
        o0b = MFMA32(av0, fuB.v, o0b); \
        o1b = MFMA32(av1, fuB.v, o1b); \
    } }

    // prologue FIFO: [K0, V0, K1] (12 outstanding)
    stageK(0);
    stageV(0);
    stageK(1);

    // step 0 (even): QK(0) only
    asm volatile("s_waitcnt vmcnt(8)" ::: "memory");
    __builtin_amdgcn_sched_barrier(0);
    QKSTEP(sEA, sEB, 0)
    __builtin_amdgcn_sched_barrier(0);
    stageV(1);
    stageK(2);
    __builtin_amdgcn_sched_barrier(0);

    // steady pairs: odd t = 2tt+1 (1..61), even t+1 = 2tt+2 (2..62)
    for (int tt = 0; tt < 31; tt++){
        int t1 = 2*tt + 1;
        // ---- odd step t1: K buf 1; FINISH prev even (V buf 0)
        asm volatile("s_waitcnt vmcnt(8)" ::: "memory");
        __builtin_amdgcn_sched_barrier(0);
        QKSTEP(sOA, sOB, KBUFSZ)
        FINISH(sEA, sEB, 0)
        __builtin_amdgcn_sched_barrier(0);
        stageV(t1 + 1);
        stageK(t1 + 2);
        __builtin_amdgcn_sched_barrier(0);
        // ---- even step t1+1: K buf 0; FINISH prev odd (V buf 1)
        asm volatile("s_waitcnt vmcnt(8)" ::: "memory");
        __builtin_amdgcn_sched_barrier(0);
        QKSTEP(sEA, sEB, 0)
        FINISH(sOA, sOB, VBUFSZ)
        __builtin_amdgcn_sched_barrier(0);
        stageV(t1 + 2);
        if (tt < 30) stageK(t1 + 3);
        __builtin_amdgcn_sched_barrier(0);
    }

    // peeled odd step t = 63: no staging
    asm volatile("s_waitcnt vmcnt(4)" ::: "memory");
    __builtin_amdgcn_sched_barrier(0);
    QKSTEP(sOA, sOB, KBUFSZ)
    FINISH(sEA, sEB, 0)                 // tile 62 (V buf 0)
    asm volatile("s_waitcnt vmcnt(0)" ::: "memory");
    __builtin_amdgcn_sched_barrier(0);
    FINISH(sOA, sOB, VBUFSZ)            // tile 63 (V buf 1)

#undef QKSTEP
#undef FINISH

    float lsA = (lpA[0] + lpA[1]) + (lpA[2] + lpA[3]);
    float lsB = (lpB[0] + lpB[1]) + (lpB[2] + lpB[3]);

    // ---- merge kv-halves via LDS, normalize, store
    lsA += __shfl_xor(lsA, 32);
    lsB += __shfl_xor(lsB, 32);
    __syncthreads();
    float* m1 = (float*)&Kl[0][0];
    float* m2 = (float*)&Vl[0][0][0];
    if (w == 1){
        #pragma unroll
        for (int r = 0; r < 16; r++){
            m1[r*64 + lane]        = o0a[r];
            m1[1024 + r*64 + lane] = o1a[r];
            m2[r*64 + lane]        = o0b[r];
            m2[1024 + r*64 + lane] = o1b[r];
        }
        if (hi == 0){ m2[2048 + ln] = lsA; m2[2048 + 32 + ln] = lsB; }
    }
    __syncthreads();
    if (w == 0){
        #pragma unroll
        for (int r = 0; r < 16; r++){
            o0a[r] += m1[r*64 + lane];
            o1a[r] += m1[1024 + r*64 + lane];
            o0b[r] += m2[r*64 + lane];
            o1b[r] += m2[1024 + r*64 + lane];
        }
        float rA = 1.0f / (lsA + m2[2048 + ln]);
        float rB = 1.0f / (lsB + m2[2048 + 32 + ln]);
        int b = bh >> 3, h = bh & 7;
        unsigned short* dstA = O + (size_t)(b*4096 + q0 + ln)*512      + h*64;
        unsigned short* dstB = O + (size_t)(b*4096 + q0 + 32 + ln)*512 + h*64;
        #pragma unroll
        for (int m = 0; m < 2; m++){
            const f32x16& ovA = m ? o1a : o0a;
            const f32x16& ovB = m ? o1b : o0b;
            #pragma unroll
            for (int g = 0; g < 4; g++){
                int d = m*32 + g*8 + hi*4;
                ushort4v pkA, pkB;
                #pragma unroll
                for (int j = 0; j < 4; j++){
                    pkA[j] = f2bf(ovA[g*4 + j] * rA);
                    pkB[j] = f2bf(ovB[g*4 + j] * rB);
                }
                *(ushort4v*)(dstA + d) = pkA;
                *(ushort4v*)(dstB + d) = pkB;
            }
        }
    }
}

// ---------------------------------------------------------------- launch
extern "C" void kernel_launch(void* const* d_in, const int* in_sizes, int n_in,
                              void* d_out, int out_size, void* d_ws, size_t ws_size,
                              hipStream_t stream) {
    const float* q    = (const float*)d_in[0];
    const float* gn_w = (const float*)d_in[1];
    const float* gn_b = (const float*)d_in[2];
    const float* wq   = (const float*)d_in[3];
    const float* bq   = (const float*)d_in[4];
    const float* wk   = (const float*)d_in[5];
    const float* bk   = (const float*)d_in[6];
    const float* wv   = (const float*)d_in[7];
    const float* bv   = (const float*)d_in[8];
    const float* wo   = (const float*)d_in[9];
    const float* bo   = (const float*)d_in[10];
    float* outp = (float*)d_out;

    char* ws = (char*)d_ws;
    float2v* parts = (float2v*)ws;                 // 512 x float2 = 4 KB
    unsigned short* xn  = (unsigned short*)(ws + 8192);
    const size_t TOK = (size_t)8192 * 512;
    unsigned short* wqkb = xn + TOK;               // 1024 x 512
    unsigned short* wvb  = wqkb + 1024*512;
    unsigned short* wob  = wvb + 512*512;
    unsigned short* Qb   = wob + 512*512;
    unsigned short* Kb   = Qb + TOK;
    unsigned short* Vt   = Kb + TOK;
    unsigned short* Ob   = Vt + TOK;

    gn_stats_wconv<<<1536, 256, 0, stream>>>(q, parts, wq, wk, wv, wo, wqkb, wvb, wob);
    gn_apply<<<dim3(64, 8, 2), 256, 0, stream>>>(q, parts, gn_w, gn_b, xn);
    gemm_qkv<<<1024, 256, 0, stream>>>(xn, wqkb, wvb, bq, bk, bv, Qb, Kb, Vt);
    attn12<<<1024, 128, 0, stream>>>(Qb, Kb, Vt, Ob);
    gemm_o2<<<dim3(64, 8), 256, 0, stream>>>(wob, Ob, bo, q, outp);
}